// Round 2
// baseline (1024.832 us; speedup 1.0000x reference)
//
#include <hip/hip_runtime.h>
#include <hip/hip_bf16.h>

typedef unsigned short u16;
typedef unsigned int u32;

#define B_ 4
#define N_ 4096
#define C_ 256
#define NH_ 8
#define HD_ 32
#define L_ 9
#define P_ 64
#define T_ 4096
#define NEG_ (-1e30f)

__device__ __forceinline__ float b2f(u16 u) {
    union { u32 i; float f; } v; v.i = ((u32)u) << 16; return v.f;
}
__device__ __forceinline__ u16 f2b(float f) {
    u32 x = __float_as_uint(f);
    u32 r = (x + 0x7fffu + ((x >> 16) & 1u)) >> 16;
    return (u16)r;
}
__device__ __forceinline__ void unpack8(uint4 u, float* dst) {
    dst[0] = b2f((u16)(u.x & 0xffff)); dst[1] = b2f((u16)(u.x >> 16));
    dst[2] = b2f((u16)(u.y & 0xffff)); dst[3] = b2f((u16)(u.y >> 16));
    dst[4] = b2f((u16)(u.z & 0xffff)); dst[5] = b2f((u16)(u.z >> 16));
    dst[6] = b2f((u16)(u.w & 0xffff)); dst[7] = b2f((u16)(u.w >> 16));
}
// load element i of an INPUT tensor whose dtype is flag-dependent
__device__ __forceinline__ float ldin(const void* p, size_t i, bool bf) {
    return bf ? b2f(((const u16*)p)[i]) : ((const float*)p)[i];
}

// ---- probe: norm_g is all-ones. bf16 -> first u32 = 0x3F803F80 ; fp32 -> 0x3F800000
__global__ void probe_k(const void* __restrict__ norm_g, int* __restrict__ flag) {
    u32 u = *(const u32*)norm_g;
    *flag = (u == 0x3F803F80u) ? 1 : 0;
}

// ---------------- generic tiled GEMM: out = A @ W^T + bias, optional exact GELU ----------------
// A: M x K row-major (ADYN: input tensor, dtype per flag; else fp32 workspace)
// W: Nn x K (input tensor, dtype per flag), out: M x Nn (ODYN: output tensor, dtype per flag; else fp32 ws)
template<int ACT, bool ADYN, bool ODYN>
__global__ __launch_bounds__(256) void gemm_k(const void* __restrict__ A, const void* __restrict__ W,
                                              const void* __restrict__ bias, void* __restrict__ out,
                                              int M, int Nn, int K, const int* __restrict__ flagp) {
    __shared__ float As[64][33];
    __shared__ float Ws[64][33];
    const bool bf = (*flagp != 0);
    const bool abf = ADYN && bf;
    int tid = threadIdx.x;
    int tx = tid & 15, ty = tid >> 4;
    int rowBase = blockIdx.y * 64, colBase = blockIdx.x * 64;
    int lr = tid >> 2, lc = (tid & 3) * 8;
    float acc[4][4] = {};
    for (int k0 = 0; k0 < K; k0 += 32) {
        size_t aoff = (size_t)(rowBase + lr) * K + k0 + lc;
        if (abf) {
            uint4 u = *reinterpret_cast<const uint4*>((const u16*)A + aoff);
            unpack8(u, &As[lr][lc]);
        } else {
            const float* ap = (const float*)A + aoff;
            float4 u0 = *reinterpret_cast<const float4*>(ap);
            float4 u1 = *reinterpret_cast<const float4*>(ap + 4);
            As[lr][lc + 0] = u0.x; As[lr][lc + 1] = u0.y; As[lr][lc + 2] = u0.z; As[lr][lc + 3] = u0.w;
            As[lr][lc + 4] = u1.x; As[lr][lc + 5] = u1.y; As[lr][lc + 6] = u1.z; As[lr][lc + 7] = u1.w;
        }
        size_t woff = (size_t)(colBase + lr) * K + k0 + lc;
        if (bf) {
            uint4 u = *reinterpret_cast<const uint4*>((const u16*)W + woff);
            unpack8(u, &Ws[lr][lc]);
        } else {
            const float* wp = (const float*)W + woff;
            float4 u0 = *reinterpret_cast<const float4*>(wp);
            float4 u1 = *reinterpret_cast<const float4*>(wp + 4);
            Ws[lr][lc + 0] = u0.x; Ws[lr][lc + 1] = u0.y; Ws[lr][lc + 2] = u0.z; Ws[lr][lc + 3] = u0.w;
            Ws[lr][lc + 4] = u1.x; Ws[lr][lc + 5] = u1.y; Ws[lr][lc + 6] = u1.z; Ws[lr][lc + 7] = u1.w;
        }
        __syncthreads();
        #pragma unroll
        for (int kk = 0; kk < 32; ++kk) {
            float av[4], bv[4];
            #pragma unroll
            for (int i = 0; i < 4; ++i) av[i] = As[ty * 4 + i][kk];
            #pragma unroll
            for (int j = 0; j < 4; ++j) bv[j] = Ws[tx * 4 + j][kk];
            #pragma unroll
            for (int i = 0; i < 4; ++i)
                #pragma unroll
                for (int j = 0; j < 4; ++j) acc[i][j] = fmaf(av[i], bv[j], acc[i][j]);
        }
        __syncthreads();
    }
    #pragma unroll
    for (int j = 0; j < 4; ++j) {
        float bj = ldin(bias, colBase + tx * 4 + j, bf);
        #pragma unroll
        for (int i = 0; i < 4; ++i) {
            float v = acc[i][j] + bj;
            if (ACT == 1) v = 0.5f * v * (1.0f + erff(v * 0.70710678118654752f));
            size_t o = (size_t)(rowBase + ty * 4 + i) * Nn + colBase + tx * 4 + j;
            if (ODYN && bf) ((u16*)out)[o] = f2b(v);
            else ((float*)out)[o] = v;
        }
    }
}

// ---------------- per-32-dim-head L2 normalize in place (first 256 cols of each row) ----------------
__global__ __launch_bounds__(256) void l2norm_heads_k(float* buf, int stride) {
    int e = blockIdx.x * 256 + threadIdx.x;
    int row = e >> 8, c = e & 255;
    size_t a = (size_t)row * stride + c;
    float v = buf[a];
    float s = v * v;
    #pragma unroll
    for (int off = 16; off >= 1; off >>= 1) s += __shfl_xor(s, off);
    float nrm = sqrtf(s);
    buf[a] = v / fmaxf(nrm, 1e-12f);
}

// ---------------- 8x8 avgpool of xg (B,N,C) -> LayerNorm -> x_pool (B,P,C) ----------------
__global__ __launch_bounds__(256) void pool_ln_k(const float* __restrict__ xg, const void* __restrict__ g,
                                                 const void* __restrict__ bta, float* __restrict__ xp,
                                                 const int* __restrict__ flagp) {
    const bool bf = (*flagp != 0);
    int bp = blockIdx.x;              // b*P + p
    int b = bp >> 6, p = bp & 63;
    int py = p >> 3, px = p & 7;
    int o = threadIdx.x;
    float s = 0.0f;
    for (int sy = 0; sy < 8; ++sy)
        #pragma unroll
        for (int sx = 0; sx < 8; ++sx) {
            int pix = (py * 8 + sy) * 64 + px * 8 + sx;
            s += xg[((size_t)(b * N_ + pix)) * C_ + o];
        }
    float v = s * (1.0f / 64.0f);
    float s1 = v, s2 = v * v;
    #pragma unroll
    for (int off = 32; off >= 1; off >>= 1) { s1 += __shfl_xor(s1, off); s2 += __shfl_xor(s2, off); }
    __shared__ float r1[4], r2[4];
    int wv = threadIdx.x >> 6, ln = threadIdx.x & 63;
    if (ln == 0) { r1[wv] = s1; r2[wv] = s2; }
    __syncthreads();
    float S1 = r1[0] + r1[1] + r1[2] + r1[3];
    float S2 = r2[0] + r2[1] + r2[2] + r2[3];
    float mu = S1 * (1.0f / 256.0f);
    float var = S2 * (1.0f / 256.0f) - mu * mu;
    float y = (v - mu) * rsqrtf(var + 1e-5f) * ldin(g, o, bf) + ldin(bta, o, bf);
    xp[(size_t)bp * C_ + o] = y;
}

// ---------------- CPB MLP: cpb[t,h] = relu(table@W1^T+b1) @ W2^T + b2 ----------------
__global__ __launch_bounds__(256) void cpb_k(const void* __restrict__ table, const void* __restrict__ w1,
                                             const void* __restrict__ b1, const void* __restrict__ w2,
                                             const void* __restrict__ b2, float* __restrict__ cpb,
                                             const int* __restrict__ flagp) {
    const bool bf = (*flagp != 0);
    int t = blockIdx.x * 256 + threadIdx.x;
    float t0 = ldin(table, t * 2, bf), t1 = ldin(table, t * 2 + 1, bf);
    float acc[8] = {};
    for (int j = 0; j < 512; ++j) {
        float h = t0 * ldin(w1, j * 2, bf) + t1 * ldin(w1, j * 2 + 1, bf) + ldin(b1, j, bf);
        h = fmaxf(h, 0.0f);
        #pragma unroll
        for (int hh = 0; hh < 8; ++hh) acc[hh] += h * ldin(w2, hh * 512 + j, bf);
    }
    #pragma unroll
    for (int hh = 0; hh < 8; ++hh) cpb[t * 8 + hh] = acc[hh] + ldin(b2, hh, bf);
}

// ---------------- fused attention: one wave per pixel per (b,h) ----------------
__global__ __launch_bounds__(256) void attn_k(const float* __restrict__ qn, const float* __restrict__ kv,
                                              const float* __restrict__ kvp, const float* __restrict__ cpb,
                                              const int* __restrict__ rpi,
                                              const void* __restrict__ temp, const void* __restrict__ qe,
                                              const void* __restrict__ lt, const void* __restrict__ rpb,
                                              const void* __restrict__ lb, const void* __restrict__ slsin,
                                              float* __restrict__ ao, const int* __restrict__ flagp) {
    __shared__ float kp_s[64 * 33];
    __shared__ float vp_s[64 * 32];
    __shared__ float qe_s[32];
    __shared__ float lt_s[288];
    __shared__ float rpb_s[9], lb_s[9];
    __shared__ float qn_s[4][32], qs_s[4][32];
    __shared__ float wgt[4][64], aw_s[4][9];

    const bool bf = (*flagp != 0);
    int bid = blockIdx.x;
    int tile = bid & 15, h = (bid >> 4) & 7, b = bid >> 7;
    int tid = threadIdx.x, wave = tid >> 6, lane = tid & 63;

    #pragma unroll
    for (int i = 0; i < 8; ++i) {
        int e = tid + i * 256;
        int p = e >> 5, d = e & 31;
        size_t base = ((size_t)(b * P_ + p)) * 512 + h * 32 + d;
        kp_s[p * 33 + d] = kvp[base];
        vp_s[p * 32 + d] = kvp[base + 256];
    }
    lt_s[tid] = ldin(lt, h * 288 + tid, bf);
    if (tid < 32) {
        lt_s[256 + tid] = ldin(lt, h * 288 + 256 + tid, bf);
        qe_s[tid] = ldin(qe, h * 32 + tid, bf);
    }
    if (tid < 9) { rpb_s[tid] = ldin(rpb, h * 9 + tid, bf); lb_s[tid] = ldin(lb, h * 9 + tid, bf); }
    float tsc = log1pf(expf(ldin(temp, h, bf)));
    __syncthreads();

    int dy = (lane < 9) ? (lane / 3 - 1) : 0;
    int dxo = (lane < 9) ? (lane % 3 - 1) : 0;

    for (int it = 0; it < 64; ++it) {
        int n = tile * 256 + wave * 64 + it;
        int y = n >> 6, x = n & 63;
        float sls = ldin(slsin, n, bf);
        if (lane < 32) {
            float qv = qn[((size_t)(b * N_ + n)) * C_ + h * 32 + lane];
            qn_s[wave][lane] = qv;
            qs_s[wave][lane] = (qv + qe_s[lane]) * tsc * sls;
        }
        __syncthreads();
        // pool logit: lane = p
        float accp = 0.0f;
        #pragma unroll
        for (int d = 0; d < 32; ++d) accp += qs_s[wave][d] * kp_s[lane * 33 + d];
        float pl = accp + cpb[(size_t)rpi[n * P_ + lane] * 8 + h];
        // local logit + learnable-token dot: lanes 0..8
        int ny = y + dy, nx = x + dxo;
        bool lval = (lane < 9) && ((unsigned)ny < 64u) && ((unsigned)nx < 64u);
        float ll = NEG_, accA = 0.0f;
        if (lane < 9) {
            const float* kb = kv + ((size_t)(b * N_ + (lval ? ny * 64 + nx : 0))) * 512 + h * 32;
            float acl = 0.0f;
            #pragma unroll
            for (int d = 0; d < 32; ++d) {
                acl  += qs_s[wave][d] * kb[d];
                accA += qn_s[wave][d] * lt_s[d * 9 + lane];
            }
            if (lval) ll = acl + rpb_s[lane];
        }
        // 73-way softmax across the wave
        float cmax = fmaxf(pl, ll);
        #pragma unroll
        for (int off = 32; off >= 1; off >>= 1) cmax = fmaxf(cmax, __shfl_xor(cmax, off));
        float ep = expf(pl - cmax);
        float el = lval ? expf(ll - cmax) : 0.0f;
        float ssum = ep + el;
        #pragma unroll
        for (int off = 32; off >= 1; off >>= 1) ssum += __shfl_xor(ssum, off);
        float inv = 1.0f / ssum;
        wgt[wave][lane] = ep * inv;
        if (lane < 9) aw_s[wave][lane] = lval ? (accA + lb_s[lane] + el * inv) : 0.0f;
        __syncthreads();
        // output: lanes 0..31 = d
        if (lane < 32) {
            float op = 0.0f;
            #pragma unroll
            for (int p = 0; p < 64; ++p) op += wgt[wave][p] * vp_s[p * 32 + lane];
            #pragma unroll
            for (int l2 = 0; l2 < 9; ++l2) {
                int nyy = y + l2 / 3 - 1, nxx = x + l2 % 3 - 1;
                if ((unsigned)nyy < 64u && (unsigned)nxx < 64u)
                    op += aw_s[wave][l2] * kv[((size_t)(b * N_ + nyy * 64 + nxx)) * 512 + 256 + h * 32 + lane];
            }
            ao[((size_t)(b * N_ + n)) * C_ + h * 32 + lane] = op;
        }
        __syncthreads();
    }
}

extern "C" void kernel_launch(void* const* d_in, const int* in_sizes, int n_in,
                              void* d_out, int out_size, void* d_ws, size_t ws_size,
                              hipStream_t stream) {
    const void* x      = d_in[0];
    const int*  rpi    = (const int*)d_in[1];
    const void* table  = d_in[2];
    const void* q_w    = d_in[3];
    const void* q_b    = d_in[4];
    const void* kv_w   = d_in[5];
    const void* kv_b   = d_in[6];
    const void* temp   = d_in[7];
    const void* qe     = d_in[8];
    const void* proj_w = d_in[9];
    const void* proj_b = d_in[10];
    const void* sr_w   = d_in[11];
    const void* sr_b   = d_in[12];
    const void* norm_g = d_in[13];
    const void* norm_b = d_in[14];
    const void* cpb1_w = d_in[15];
    const void* cpb1_b = d_in[16];
    const void* cpb2_w = d_in[17];
    const void* cpb2_b = d_in[18];
    const void* rpb    = d_in[19];
    const void* lt     = d_in[20];
    const void* lb     = d_in[21];
    const void* sls    = d_in[22];

    float* ws  = (float*)d_ws;
    float* qn  = ws;                                  // B*N*C
    float* kv  = qn  + (size_t)B_ * N_ * C_;          // B*N*2C
    float* ao  = kv  + (size_t)B_ * N_ * 2 * C_;      // B*N*C  (aliased: xg then attn out)
    float* xp  = ao  + (size_t)B_ * N_ * C_;          // B*P*C
    float* kvp = xp  + (size_t)B_ * P_ * C_;          // B*P*2C
    float* cpb = kvp + (size_t)B_ * P_ * 2 * C_;      // T*NH
    int*   flag = (int*)(cpb + (size_t)T_ * NH_);

    const int M = B_ * N_;
    dim3 blk(256);

    probe_k<<<dim3(1), dim3(1), 0, stream>>>(norm_g, flag);

    // q = x @ q_w^T + q_b ; per-head l2norm in place
    gemm_k<0, true, false><<<dim3(C_ / 64, M / 64), blk, 0, stream>>>(x, q_w, q_b, qn, M, C_, C_, flag);
    l2norm_heads_k<<<dim3(M), blk, 0, stream>>>(qn, C_);
    // kv = x @ kv_w^T + kv_b ; normalize k part per head
    gemm_k<0, true, false><<<dim3(2 * C_ / 64, M / 64), blk, 0, stream>>>(x, kv_w, kv_b, kv, M, 2 * C_, C_, flag);
    l2norm_heads_k<<<dim3(M), blk, 0, stream>>>(kv, 2 * C_);
    // xg = gelu(x @ sr_w^T + sr_b)  (stored in ao buffer, consumed by pool_ln)
    gemm_k<1, true, false><<<dim3(C_ / 64, M / 64), blk, 0, stream>>>(x, sr_w, sr_b, ao, M, C_, C_, flag);
    pool_ln_k<<<dim3(B_ * P_), blk, 0, stream>>>(ao, norm_g, norm_b, xp, flag);
    // kv_pool = x_pool @ kv_w^T + kv_b ; normalize k part
    gemm_k<0, false, false><<<dim3(2 * C_ / 64, (B_ * P_) / 64), blk, 0, stream>>>(xp, kv_w, kv_b, kvp, B_ * P_, 2 * C_, C_, flag);
    l2norm_heads_k<<<dim3(B_ * P_), blk, 0, stream>>>(kvp, 2 * C_);
    // cpb table
    cpb_k<<<dim3(T_ / 256), blk, 0, stream>>>(table, cpb1_w, cpb1_b, cpb2_w, cpb2_b, cpb, flag);
    // fused attention -> ao (overwrites xg)
    attn_k<<<dim3(B_ * NH_ * 16), blk, 0, stream>>>(qn, kv, kvp, cpb, rpi, temp, qe, lt, rpb, lb, sls, ao, flag);
    // out = ao @ proj_w^T + proj_b  (dtype per flag)
    gemm_k<0, false, true><<<dim3(C_ / 64, M / 64), blk, 0, stream>>>(ao, proj_w, proj_b, d_out, M, C_, C_, flag);
}

// Round 4
// 489.771 us; speedup vs baseline: 2.0925x; 2.0925x over previous
//
#include <hip/hip_runtime.h>
#include <hip/hip_bf16.h>

typedef unsigned short u16;
typedef unsigned int u32;

#define B_ 4
#define N_ 4096
#define C_ 256
#define NH_ 8
#define HD_ 32
#define L_ 9
#define P_ 64
#define T_ 4096
#define NEG_ (-1e30f)

typedef __attribute__((ext_vector_type(8))) short bf16x8;
typedef __attribute__((ext_vector_type(4))) float f32x4;

__device__ __forceinline__ u16 f2b(float f) {
    u32 x = __float_as_uint(f);
    u32 r = (x + 0x7fffu + ((x >> 16) & 1u)) >> 16;
    return (u16)r;
}

// ---------------- fp32 -> bf16 convert (grid-stride, 4 elems/thread) ----------------
__global__ __launch_bounds__(256) void cvt_k(const float* __restrict__ src, u16* __restrict__ dst, int n4) {
    for (int i = blockIdx.x * 256 + threadIdx.x; i < n4; i += gridDim.x * 256) {
        float4 v = reinterpret_cast<const float4*>(src)[i];
        ushort4 o;
        o.x = f2b(v.x); o.y = f2b(v.y); o.z = f2b(v.z); o.w = f2b(v.w);
        reinterpret_cast<ushort4*>(dst)[i] = o;
    }
}

// ---------------- MFMA GEMM: out = A @ W^T + bias (A,W bf16; bias,out fp32) ----------------
// block = 4 waves, tile 64(M) x 64(N); wave w -> rows [w*16, w*16+16), 4 col-subtiles of 16
template<int ACT, int OBF>
__global__ __launch_bounds__(256) void gemm_mfma_k(const u16* __restrict__ A, const u16* __restrict__ W,
                                                   const float* __restrict__ bias, void* __restrict__ out,
                                                   int Nn, int K) {
    int tid = threadIdx.x;
    int wv = tid >> 6, lane = tid & 63;
    int quad = lane >> 4, l16 = lane & 15;
    int rowBase = blockIdx.y * 64 + wv * 16;
    int colBase = blockIdx.x * 64;
    f32x4 acc[4] = {};
    const u16* aptr = A + (size_t)(rowBase + l16) * K + quad * 8;
    const u16* wptr = W + (size_t)(colBase + l16) * K + quad * 8;
    for (int k0 = 0; k0 < K; k0 += 32) {
        bf16x8 af = *reinterpret_cast<const bf16x8*>(aptr + k0);
        #pragma unroll
        for (int j = 0; j < 4; ++j) {
            bf16x8 bfr = *reinterpret_cast<const bf16x8*>(wptr + (size_t)j * 16 * K + k0);
            acc[j] = __builtin_amdgcn_mfma_f32_16x16x32_bf16(af, bfr, acc[j], 0, 0, 0);
        }
    }
    #pragma unroll
    for (int j = 0; j < 4; ++j) {
        int col = colBase + j * 16 + l16;
        float bj = bias[col];
        #pragma unroll
        for (int r = 0; r < 4; ++r) {
            int row = rowBase + quad * 4 + r;
            float v = acc[j][r] + bj;
            if (ACT == 1) v = 0.5f * v * (1.0f + erff(v * 0.70710678118654752f));
            size_t o = (size_t)row * Nn + col;
            if (OBF) ((u16*)out)[o] = f2b(v);
            else ((float*)out)[o] = v;
        }
    }
}

// ---------------- small fp32 GEMM (kv_pool only, M=256): out = A @ W^T + bias ----------------
__global__ __launch_bounds__(256) void gemm_f32_k(const float* __restrict__ A, const float* __restrict__ W,
                                                  const float* __restrict__ bias, float* __restrict__ out,
                                                  int Nn, int K) {
    __shared__ float As[64][33];
    __shared__ float Ws[64][33];
    int tid = threadIdx.x;
    int tx = tid & 15, ty = tid >> 4;
    int rowBase = blockIdx.y * 64, colBase = blockIdx.x * 64;
    int lr = tid >> 2, lc = (tid & 3) * 8;
    float acc[4][4] = {};
    for (int k0 = 0; k0 < K; k0 += 32) {
        const float* ap = A + (size_t)(rowBase + lr) * K + k0 + lc;
        #pragma unroll
        for (int i = 0; i < 8; ++i) As[lr][lc + i] = ap[i];
        const float* wp = W + (size_t)(colBase + lr) * K + k0 + lc;
        #pragma unroll
        for (int i = 0; i < 8; ++i) Ws[lr][lc + i] = wp[i];
        __syncthreads();
        #pragma unroll
        for (int kk = 0; kk < 32; ++kk) {
            float av[4], bv[4];
            #pragma unroll
            for (int i = 0; i < 4; ++i) av[i] = As[ty * 4 + i][kk];
            #pragma unroll
            for (int j = 0; j < 4; ++j) bv[j] = Ws[tx * 4 + j][kk];
            #pragma unroll
            for (int i = 0; i < 4; ++i)
                #pragma unroll
                for (int j = 0; j < 4; ++j) acc[i][j] = fmaf(av[i], bv[j], acc[i][j]);
        }
        __syncthreads();
    }
    #pragma unroll
    for (int j = 0; j < 4; ++j) {
        float bj = bias[colBase + tx * 4 + j];
        #pragma unroll
        for (int i = 0; i < 4; ++i)
            out[(size_t)(rowBase + ty * 4 + i) * Nn + colBase + tx * 4 + j] = acc[i][j] + bj;
    }
}

// ---------------- per-32-dim-head L2 normalize in place (first 256 cols of each row) ----------------
__global__ __launch_bounds__(256) void l2norm_heads_k(float* buf, int stride) {
    int e = blockIdx.x * 256 + threadIdx.x;
    int row = e >> 8, c = e & 255;
    size_t a = (size_t)row * stride + c;
    float v = buf[a];
    float s = v * v;
    #pragma unroll
    for (int off = 16; off >= 1; off >>= 1) s += __shfl_xor(s, off);
    buf[a] = v / fmaxf(sqrtf(s), 1e-12f);
}

// ---------------- 8x8 avgpool of xg (B,N,C) -> LayerNorm -> x_pool (B,P,C) fp32 ----------------
__global__ __launch_bounds__(256) void pool_ln_k(const float* __restrict__ xg, const float* __restrict__ g,
                                                 const float* __restrict__ bta, float* __restrict__ xp) {
    int bp = blockIdx.x;
    int b = bp >> 6, p = bp & 63;
    int py = p >> 3, px = p & 7;
    int o = threadIdx.x;
    float s = 0.0f;
    for (int sy = 0; sy < 8; ++sy)
        #pragma unroll
        for (int sx = 0; sx < 8; ++sx) {
            int pix = (py * 8 + sy) * 64 + px * 8 + sx;
            s += xg[((size_t)(b * N_ + pix)) * C_ + o];
        }
    float v = s * (1.0f / 64.0f);
    float s1 = v, s2 = v * v;
    #pragma unroll
    for (int off = 32; off >= 1; off >>= 1) { s1 += __shfl_xor(s1, off); s2 += __shfl_xor(s2, off); }
    __shared__ float r1[4], r2[4];
    int wv = threadIdx.x >> 6, ln = threadIdx.x & 63;
    if (ln == 0) { r1[wv] = s1; r2[wv] = s2; }
    __syncthreads();
    float S1 = r1[0] + r1[1] + r1[2] + r1[3];
    float S2 = r2[0] + r2[1] + r2[2] + r2[3];
    float mu = S1 * (1.0f / 256.0f);
    float var = S2 * (1.0f / 256.0f) - mu * mu;
    xp[(size_t)bp * C_ + o] = (v - mu) * rsqrtf(var + 1e-5f) * g[o] + bta[o];
}

// ---------------- CPB MLP with LDS-staged weights ----------------
__global__ __launch_bounds__(256) void cpb_k(const float* __restrict__ table, const float* __restrict__ w1,
                                             const float* __restrict__ b1, const float* __restrict__ w2,
                                             const float* __restrict__ b2, float* __restrict__ cpb) {
    __shared__ float w1s[512][2];
    __shared__ float b1s[512];
    __shared__ float w2s[8][512];
    int tid = threadIdx.x;
    for (int i = tid; i < 512; i += 256) {
        w1s[i][0] = w1[i * 2]; w1s[i][1] = w1[i * 2 + 1]; b1s[i] = b1[i];
    }
    for (int i = tid; i < 4096; i += 256) w2s[i >> 9][i & 511] = w2[i];
    __syncthreads();
    int t = blockIdx.x * 256 + tid;
    float t0 = table[t * 2], t1 = table[t * 2 + 1];
    float acc[8] = {};
    for (int j = 0; j < 512; ++j) {
        float h = fmaxf(t0 * w1s[j][0] + t1 * w1s[j][1] + b1s[j], 0.0f);
        #pragma unroll
        for (int hh = 0; hh < 8; ++hh) acc[hh] += h * w2s[hh][j];
    }
    #pragma unroll
    for (int hh = 0; hh < 8; ++hh) cpb[t * 8 + hh] = acc[hh] + b2[hh];
}

// ---------------- fused attention: block = (b, h, 64-pixel tile); 4 waves x 16 pixels ----------------
__global__ __launch_bounds__(256) void attn_k(const float* __restrict__ qn, const float* __restrict__ kv,
                                              const float* __restrict__ kvp, const float* __restrict__ cpb,
                                              const int* __restrict__ rpi,
                                              const float* __restrict__ temp, const float* __restrict__ qe,
                                              const float* __restrict__ lt, const float* __restrict__ rpb,
                                              const float* __restrict__ lb, const float* __restrict__ slsin,
                                              u16* __restrict__ aob) {
    __shared__ float kp_s[64 * 33];
    __shared__ float vp_s[64 * 32];
    __shared__ float qe_s[32];
    __shared__ float lt_s[288];
    __shared__ float rpb_s[9], lb_s[9];
    __shared__ float qn_s[4][32], qs_s[4][32];
    __shared__ float wgt[4][64], aw_s[4][9];

    int bid = blockIdx.x;
    int tile = bid & 63, h = (bid >> 6) & 7, b = bid >> 9;
    int tid = threadIdx.x, wave = tid >> 6, lane = tid & 63;

    #pragma unroll
    for (int i = 0; i < 8; ++i) {
        int e = tid + i * 256;
        int p = e >> 5, d = e & 31;
        size_t base = ((size_t)(b * P_ + p)) * 512 + h * 32 + d;
        kp_s[p * 33 + d] = kvp[base];
        vp_s[p * 32 + d] = kvp[base + 256];
    }
    lt_s[tid] = lt[h * 288 + tid];
    if (tid < 32) {
        lt_s[256 + tid] = lt[h * 288 + 256 + tid];
        qe_s[tid] = qe[h * 32 + tid];
    }
    if (tid < 9) { rpb_s[tid] = rpb[h * 9 + tid]; lb_s[tid] = lb[h * 9 + tid]; }
    float tsc = log1pf(expf(temp[h]));
    __syncthreads();

    int dy = (lane < 9) ? (lane / 3 - 1) : 0;
    int dxo = (lane < 9) ? (lane % 3 - 1) : 0;

    for (int it = 0; it < 16; ++it) {
        int n = tile * 64 + wave * 16 + it;
        int y = n >> 6, x = n & 63;
        // ---- early issue: independent loads ----
        int pidx = rpi[n * P_ + lane];
        float sls = slsin[n];
        float qv = 0.0f;
        if (lane < 32) qv = qn[((size_t)(b * N_ + n)) * C_ + h * 32 + lane];
        float vv[9];
        if (lane < 32) {
            #pragma unroll
            for (int l2 = 0; l2 < 9; ++l2) {
                int nyy = y + l2 / 3 - 1, nxx = x + l2 % 3 - 1;
                bool ok = ((unsigned)nyy < 64u) && ((unsigned)nxx < 64u);
                vv[l2] = kv[((size_t)(b * N_ + (ok ? nyy * 64 + nxx : 0))) * 512 + 256 + h * 32 + lane];
            }
        }
        float pb = cpb[(size_t)pidx * 8 + h];
        if (lane < 32) {
            qn_s[wave][lane] = qv;
            qs_s[wave][lane] = (qv + qe_s[lane]) * tsc * sls;
        }
        // (no barrier: qn_s/qs_s/wgt/aw_s are per-wave private; in-wave LDS order is guaranteed)
        // ---- pool logit: lane = p ----
        float accp = 0.0f;
        #pragma unroll
        for (int d = 0; d < 32; ++d) accp += qs_s[wave][d] * kp_s[lane * 33 + d];
        float pl = accp + pb;
        // ---- local logit + learnable-token dot: lanes 0..8 ----
        int ny = y + dy, nx = x + dxo;
        bool lval = (lane < 9) && ((unsigned)ny < 64u) && ((unsigned)nx < 64u);
        float ll = NEG_, accA = 0.0f;
        if (lane < 9) {
            const float4* kb4 = reinterpret_cast<const float4*>(
                kv + ((size_t)(b * N_ + (lval ? ny * 64 + nx : 0))) * 512 + h * 32);
            float acl = 0.0f;
            #pragma unroll
            for (int d4 = 0; d4 < 8; ++d4) {
                float4 kk = kb4[d4];
                acl += qs_s[wave][d4 * 4 + 0] * kk.x + qs_s[wave][d4 * 4 + 1] * kk.y
                     + qs_s[wave][d4 * 4 + 2] * kk.z + qs_s[wave][d4 * 4 + 3] * kk.w;
            }
            #pragma unroll
            for (int d = 0; d < 32; ++d) accA += qn_s[wave][d] * lt_s[d * 9 + lane];
            if (lval) ll = acl + rpb_s[lane];
        }
        // ---- 73-way softmax across the wave ----
        float cmax = fmaxf(pl, ll);
        #pragma unroll
        for (int off = 32; off >= 1; off >>= 1) cmax = fmaxf(cmax, __shfl_xor(cmax, off));
        float ep = expf(pl - cmax);
        float el = lval ? expf(ll - cmax) : 0.0f;
        float ssum = ep + el;
        #pragma unroll
        for (int off = 32; off >= 1; off >>= 1) ssum += __shfl_xor(ssum, off);
        float inv = 1.0f / ssum;
        wgt[wave][lane] = ep * inv;
        if (lane < 9) aw_s[wave][lane] = lval ? (accA + lb_s[lane] + el * inv) : 0.0f;
        // ---- output: lanes 0..31 = d ----
        if (lane < 32) {
            float op = 0.0f;
            #pragma unroll
            for (int p = 0; p < 64; ++p) op += wgt[wave][p] * vp_s[p * 32 + lane];
            #pragma unroll
            for (int l2 = 0; l2 < 9; ++l2) op += aw_s[wave][l2] * vv[l2];
            aob[((size_t)(b * N_ + n)) * C_ + h * 32 + lane] = f2b(op);
        }
    }
}

extern "C" void kernel_launch(void* const* d_in, const int* in_sizes, int n_in,
                              void* d_out, int out_size, void* d_ws, size_t ws_size,
                              hipStream_t stream) {
    const float* x      = (const float*)d_in[0];
    const int*   rpi    = (const int*)d_in[1];
    const float* table  = (const float*)d_in[2];
    const float* q_w    = (const float*)d_in[3];
    const float* q_b    = (const float*)d_in[4];
    const float* kv_w   = (const float*)d_in[5];
    const float* kv_b   = (const float*)d_in[6];
    const float* temp   = (const float*)d_in[7];
    const float* qe     = (const float*)d_in[8];
    const float* proj_w = (const float*)d_in[9];
    const float* proj_b = (const float*)d_in[10];
    const float* sr_w   = (const float*)d_in[11];
    const float* sr_b   = (const float*)d_in[12];
    const float* norm_g = (const float*)d_in[13];
    const float* norm_b = (const float*)d_in[14];
    const float* cpb1_w = (const float*)d_in[15];
    const float* cpb1_b = (const float*)d_in[16];
    const float* cpb2_w = (const float*)d_in[17];
    const float* cpb2_b = (const float*)d_in[18];
    const float* rpb    = (const float*)d_in[19];
    const float* lt     = (const float*)d_in[20];
    const float* lb     = (const float*)d_in[21];
    const float* sls    = (const float*)d_in[22];

    float* ws  = (float*)d_ws;
    float* qn  = ws;                                  // B*N*C fp32
    float* kv  = qn  + (size_t)B_ * N_ * C_;          // B*N*2C fp32
    float* xg  = kv  + (size_t)B_ * N_ * 2 * C_;      // B*N*C fp32 (reused as bf16 attn out)
    float* xp  = xg  + (size_t)B_ * N_ * C_;          // B*P*C fp32
    float* kvp = xp  + (size_t)B_ * P_ * C_;          // B*P*2C fp32
    float* cpb = kvp + (size_t)B_ * P_ * 2 * C_;      // T*NH fp32
    u16*   xb  = (u16*)(cpb + (size_t)T_ * NH_);      // B*N*C bf16
    u16*   qwb = xb  + (size_t)B_ * N_ * C_;          // C*C bf16
    u16*   kwb = qwb + (size_t)C_ * C_;               // 2C*C bf16
    u16*   swb = kwb + (size_t)2 * C_ * C_;           // C*C bf16
    u16*   pwb = swb + (size_t)C_ * C_;               // C*C bf16
    u16*   aob = (u16*)xg;                            // B*N*C bf16 (xg dead after pool_ln)

    const int M = B_ * N_;
    dim3 blk(256);

    // fp32 -> bf16 conversions
    cvt_k<<<dim3(1024), blk, 0, stream>>>(x, xb, (B_ * N_ * C_) / 4);
    cvt_k<<<dim3(64), blk, 0, stream>>>(q_w, qwb, (C_ * C_) / 4);
    cvt_k<<<dim3(128), blk, 0, stream>>>(kv_w, kwb, (2 * C_ * C_) / 4);
    cvt_k<<<dim3(64), blk, 0, stream>>>(sr_w, swb, (C_ * C_) / 4);
    cvt_k<<<dim3(64), blk, 0, stream>>>(proj_w, pwb, (C_ * C_) / 4);

    // q = x @ q_w^T + q_b ; per-head l2norm in place
    gemm_mfma_k<0, 0><<<dim3(C_ / 64, M / 64), blk, 0, stream>>>(xb, qwb, q_b, qn, C_, C_);
    l2norm_heads_k<<<dim3(M), blk, 0, stream>>>(qn, C_);
    // kv = x @ kv_w^T + kv_b ; normalize k part per head
    gemm_mfma_k<0, 0><<<dim3(2 * C_ / 64, M / 64), blk, 0, stream>>>(xb, kwb, kv_b, kv, 2 * C_, C_);
    l2norm_heads_k<<<dim3(M), blk, 0, stream>>>(kv, 2 * C_);
    // xg = gelu(x @ sr_w^T + sr_b)
    gemm_mfma_k<1, 0><<<dim3(C_ / 64, M / 64), blk, 0, stream>>>(xb, swb, sr_b, xg, C_, C_);
    pool_ln_k<<<dim3(B_ * P_), blk, 0, stream>>>(xg, norm_g, norm_b, xp);
    // kv_pool = x_pool @ kv_w^T + kv_b ; normalize k part (fp32, tiny)
    gemm_f32_k<<<dim3(2 * C_ / 64, (B_ * P_) / 64), blk, 0, stream>>>(xp, kv_w, kv_b, kvp, 2 * C_, C_);
    l2norm_heads_k<<<dim3(B_ * P_), blk, 0, stream>>>(kvp, 2 * C_);
    // cpb table
    cpb_k<<<dim3(T_ / 256), blk, 0, stream>>>(table, cpb1_w, cpb1_b, cpb2_w, cpb2_b, cpb);
    // fused attention -> aob (bf16)
    attn_k<<<dim3(B_ * NH_ * 64), blk, 0, stream>>>(qn, kv, kvp, cpb, rpi, temp, qe, lt, rpb, lb, sls, aob);
    // out = aob @ proj_w^T + proj_b  (fp32 out)
    gemm_mfma_k<0, 0><<<dim3(C_ / 64, M / 64), blk, 0, stream>>>(aob, pwb, proj_b, d_out, C_, C_);
}

// Round 5
// 364.269 us; speedup vs baseline: 2.8134x; 1.3445x over previous
//
#include <hip/hip_runtime.h>
#include <hip/hip_bf16.h>

typedef unsigned short u16;
typedef unsigned int u32;

#define B_ 4
#define N_ 4096
#define C_ 256
#define NH_ 8
#define HD_ 32
#define L_ 9
#define P_ 64
#define T_ 4096
#define NEG_ (-1e30f)

typedef __attribute__((ext_vector_type(8))) short bf16x8;
typedef __attribute__((ext_vector_type(4))) float f32x4;

__device__ __forceinline__ float b2f(u16 u) {
    union { u32 i; float f; } v; v.i = ((u32)u) << 16; return v.f;
}
__device__ __forceinline__ u16 f2b(float f) {
    u32 x = __float_as_uint(f);
    u32 r = (x + 0x7fffu + ((x >> 16) & 1u)) >> 16;
    return (u16)r;
}
__device__ __forceinline__ short f2bs(float f) { return (short)f2b(f); }

// ---------------- one-shot bf16 conversion of the 4 GEMM weight matrices ----------------
__global__ __launch_bounds__(256) void cvtw_k(const float* __restrict__ s0, const float* __restrict__ s1,
                                              const float* __restrict__ s2, const float* __restrict__ s3,
                                              u16* __restrict__ d0, u16* __restrict__ d1,
                                              u16* __restrict__ d2, u16* __restrict__ d3) {
    int i = blockIdx.x * 256 + threadIdx.x;   // float4 index, total 81920
    const float* s; u16* d; int off;
    if (i < 16384)      { s = s0; d = d0; off = i; }
    else if (i < 49152) { s = s1; d = d1; off = i - 16384; }
    else if (i < 65536) { s = s2; d = d2; off = i - 49152; }
    else                { s = s3; d = d3; off = i - 65536; }
    float4 v = reinterpret_cast<const float4*>(s)[off];
    ushort4 o; o.x = f2b(v.x); o.y = f2b(v.y); o.z = f2b(v.z); o.w = f2b(v.w);
    reinterpret_cast<ushort4*>(d)[off] = o;
}

// ---------------- MFMA GEMM: out = A @ W^T + bias; optional GELU; optional fused per-head l2norm ----
// NORM: 0 none, 1 all cols, 2 only cols < 256 (k-part of kv). AF32: A is fp32 (inline-converted).
template<int ACT, int NORM, int AF32>
__global__ __launch_bounds__(256) void gemm_mfma_k(const void* __restrict__ A_, const u16* __restrict__ W,
                                                   const float* __restrict__ bias, float* __restrict__ out,
                                                   int Nn, int K) {
    int tid = threadIdx.x;
    int wv = tid >> 6, lane = tid & 63;
    int quad = lane >> 4, l16 = lane & 15;
    int rowBase = blockIdx.y * 64 + wv * 16;
    int colBase = blockIdx.x * 64;
    f32x4 acc[4] = {};
    const u16* wptr = W + (size_t)(colBase + l16) * K + quad * 8;
    const u16* aptr_b = (const u16*)A_ + (size_t)(rowBase + l16) * K + quad * 8;
    const float* aptr_f = (const float*)A_ + (size_t)(rowBase + l16) * K + quad * 8;
    for (int k0 = 0; k0 < K; k0 += 32) {
        bf16x8 af;
        if (AF32) {
            float4 a0 = *reinterpret_cast<const float4*>(aptr_f + k0);
            float4 a1 = *reinterpret_cast<const float4*>(aptr_f + k0 + 4);
            af[0] = f2bs(a0.x); af[1] = f2bs(a0.y); af[2] = f2bs(a0.z); af[3] = f2bs(a0.w);
            af[4] = f2bs(a1.x); af[5] = f2bs(a1.y); af[6] = f2bs(a1.z); af[7] = f2bs(a1.w);
        } else {
            af = *reinterpret_cast<const bf16x8*>(aptr_b + k0);
        }
        #pragma unroll
        for (int j = 0; j < 4; ++j) {
            bf16x8 bfr = *reinterpret_cast<const bf16x8*>(wptr + (size_t)j * 16 * K + k0);
            acc[j] = __builtin_amdgcn_mfma_f32_16x16x32_bf16(af, bfr, acc[j], 0, 0, 0);
        }
    }
    float v[4][4];
    #pragma unroll
    for (int j = 0; j < 4; ++j) {
        float bj = bias[colBase + j * 16 + l16];
        #pragma unroll
        for (int r = 0; r < 4; ++r) {
            float t = acc[j][r] + bj;
            if (ACT == 1) t = 0.5f * t * (1.0f + erff(t * 0.70710678118654752f));
            v[j][r] = t;
        }
    }
    if (NORM == 1 || (NORM == 2 && colBase < 256)) {
        // per-head (32-col) l2norm: sum over j-pair and the 16 l16 lanes
        #pragma unroll
        for (int hp = 0; hp < 2; ++hp)
            #pragma unroll
            for (int r = 0; r < 4; ++r) {
                float s = v[2*hp][r] * v[2*hp][r] + v[2*hp+1][r] * v[2*hp+1][r];
                s += __shfl_xor(s, 1); s += __shfl_xor(s, 2);
                s += __shfl_xor(s, 4); s += __shfl_xor(s, 8);
                float inv = 1.0f / fmaxf(sqrtf(s), 1e-12f);
                v[2*hp][r] *= inv; v[2*hp+1][r] *= inv;
            }
    }
    #pragma unroll
    for (int j = 0; j < 4; ++j)
        #pragma unroll
        for (int r = 0; r < 4; ++r)
            out[(size_t)(rowBase + quad*4 + r) * Nn + colBase + j*16 + l16] = v[j][r];
}

// ---------------- small fp32 GEMM (kv_pool only, M=256) ----------------
__global__ __launch_bounds__(256) void gemm_f32_k(const float* __restrict__ A, const float* __restrict__ W,
                                                  const float* __restrict__ bias, float* __restrict__ out,
                                                  int Nn, int K) {
    __shared__ float As[64][33];
    __shared__ float Ws[64][33];
    int tid = threadIdx.x;
    int tx = tid & 15, ty = tid >> 4;
    int rowBase = blockIdx.y * 64, colBase = blockIdx.x * 64;
    int lr = tid >> 2, lc = (tid & 3) * 8;
    float acc[4][4] = {};
    for (int k0 = 0; k0 < K; k0 += 32) {
        const float* ap = A + (size_t)(rowBase + lr) * K + k0 + lc;
        #pragma unroll
        for (int i = 0; i < 8; ++i) As[lr][lc + i] = ap[i];
        const float* wp = W + (size_t)(colBase + lr) * K + k0 + lc;
        #pragma unroll
        for (int i = 0; i < 8; ++i) Ws[lr][lc + i] = wp[i];
        __syncthreads();
        #pragma unroll
        for (int kk = 0; kk < 32; ++kk) {
            float av[4], bv[4];
            #pragma unroll
            for (int i = 0; i < 4; ++i) av[i] = As[ty * 4 + i][kk];
            #pragma unroll
            for (int j = 0; j < 4; ++j) bv[j] = Ws[tx * 4 + j][kk];
            #pragma unroll
            for (int i = 0; i < 4; ++i)
                #pragma unroll
                for (int j = 0; j < 4; ++j) acc[i][j] = fmaf(av[i], bv[j], acc[i][j]);
        }
        __syncthreads();
    }
    #pragma unroll
    for (int j = 0; j < 4; ++j) {
        float bj = bias[colBase + tx * 4 + j];
        #pragma unroll
        for (int i = 0; i < 4; ++i)
            out[(size_t)(rowBase + ty * 4 + i) * Nn + colBase + tx * 4 + j] = acc[i][j] + bj;
    }
}

// ---------------- per-32-dim-head L2 normalize in place (first 256 cols of each row) ----------------
__global__ __launch_bounds__(256) void l2norm_heads_k(float* buf, int stride) {
    int e = blockIdx.x * 256 + threadIdx.x;
    int row = e >> 8, c = e & 255;
    size_t a = (size_t)row * stride + c;
    float v = buf[a];
    float s = v * v;
    #pragma unroll
    for (int off = 16; off >= 1; off >>= 1) s += __shfl_xor(s, off);
    buf[a] = v / fmaxf(sqrtf(s), 1e-12f);
}

// ---------------- 8x8 avgpool of xg (B,N,C) -> LayerNorm -> x_pool (B,P,C) fp32 ----------------
__global__ __launch_bounds__(256) void pool_ln_k(const float* __restrict__ xg, const float* __restrict__ g,
                                                 const float* __restrict__ bta, float* __restrict__ xp) {
    int bp = blockIdx.x;
    int b = bp >> 6, p = bp & 63;
    int py = p >> 3, px = p & 7;
    int o = threadIdx.x;
    float s = 0.0f;
    for (int sy = 0; sy < 8; ++sy)
        #pragma unroll
        for (int sx = 0; sx < 8; ++sx) {
            int pix = (py * 8 + sy) * 64 + px * 8 + sx;
            s += xg[((size_t)(b * N_ + pix)) * C_ + o];
        }
    float v = s * (1.0f / 64.0f);
    float s1 = v, s2 = v * v;
    #pragma unroll
    for (int off = 32; off >= 1; off >>= 1) { s1 += __shfl_xor(s1, off); s2 += __shfl_xor(s2, off); }
    __shared__ float r1[4], r2[4];
    int wv = threadIdx.x >> 6, ln = threadIdx.x & 63;
    if (ln == 0) { r1[wv] = s1; r2[wv] = s2; }
    __syncthreads();
    float S1 = r1[0] + r1[1] + r1[2] + r1[3];
    float S2 = r2[0] + r2[1] + r2[2] + r2[3];
    float mu = S1 * (1.0f / 256.0f);
    float var = S2 * (1.0f / 256.0f) - mu * mu;
    xp[(size_t)bp * C_ + o] = (v - mu) * rsqrtf(var + 1e-5f) * g[o] + bta[o];
}

// ---------------- CPB MLP with LDS-staged weights ----------------
__global__ __launch_bounds__(256) void cpb_k(const float* __restrict__ table, const float* __restrict__ w1,
                                             const float* __restrict__ b1, const float* __restrict__ w2,
                                             const float* __restrict__ b2, float* __restrict__ cpb) {
    __shared__ float w1s[512][2];
    __shared__ float b1s[512];
    __shared__ float w2s[8][512];
    int tid = threadIdx.x;
    for (int i = tid; i < 512; i += 256) {
        w1s[i][0] = w1[i * 2]; w1s[i][1] = w1[i * 2 + 1]; b1s[i] = b1[i];
    }
    for (int i = tid; i < 4096; i += 256) w2s[i >> 9][i & 511] = w2[i];
    __syncthreads();
    int t = blockIdx.x * 256 + tid;
    float t0 = table[t * 2], t1 = table[t * 2 + 1];
    float acc[8] = {};
    for (int j = 0; j < 512; ++j) {
        float h = fmaxf(t0 * w1s[j][0] + t1 * w1s[j][1] + b1s[j], 0.0f);
        #pragma unroll
        for (int hh = 0; hh < 8; ++hh) acc[hh] += h * w2s[hh][j];
    }
    #pragma unroll
    for (int hh = 0; hh < 8; ++hh) cpb[t * 8 + hh] = acc[hh] + b2[hh];
}

// ---------------- MFMA fused attention: block = (b, h, 64-pixel tile); wave = 16 pixels ----------------
// Pool logits / learnable-token logits / PV through the matrix pipe (hi/lo bf16 compensated splits);
// 3x3 local logits and local-V stay fp32 VALU.
__global__ __launch_bounds__(256) void attn_k(
    const float* __restrict__ qn, const float* __restrict__ kv,
    const float* __restrict__ kvp, const float* __restrict__ cpb,
    const int* __restrict__ rpi, const float* __restrict__ temp,
    const float* __restrict__ qe, const float* __restrict__ lt,
    const float* __restrict__ rpb, const float* __restrict__ lb,
    const float* __restrict__ slsin, u16* __restrict__ aob)
{
    __shared__ u16 kp_hi[64 * 40], kp_lo[64 * 40];       // Kp rows, B-frag friendly
    __shared__ u16 vp_hi[32 * 72], vp_lo[32 * 72];       // Vp^T rows
    __shared__ u16 ltb[16 * 32];                          // lt^T rows (l, d)
    __shared__ float qs_w[4][16][36];                     // per-wave scaled q (fp32)
    __shared__ float S_w[4][16][88];                      // logits / weights / aw (cols 76..84)
    __shared__ float rpb_s[9], lb_s[9];

    int bid = blockIdx.x;
    int tile = bid & 63, h = (bid >> 6) & 7, b = bid >> 9;
    int tid = threadIdx.x, wave = tid >> 6, lane = tid & 63;
    int quad = lane >> 4, l16 = lane & 15;

    // ---- stage Kp (hi/lo) and Vp^T (hi/lo) ----
    {
        int p = tid >> 2, dc = (tid & 3) * 8;
        const float* src = kvp + ((size_t)(b * P_ + p)) * 512 + h * 32 + dc;
        float4 k0 = *(const float4*)(src), k1 = *(const float4*)(src + 4);
        float4 v0 = *(const float4*)(src + 256), v1 = *(const float4*)(src + 260);
        float kf[8] = {k0.x,k0.y,k0.z,k0.w,k1.x,k1.y,k1.z,k1.w};
        float vf[8] = {v0.x,v0.y,v0.z,v0.w,v1.x,v1.y,v1.z,v1.w};
        #pragma unroll
        for (int j = 0; j < 8; ++j) {
            u16 khi = f2b(kf[j]);
            kp_hi[p * 40 + dc + j] = khi;
            kp_lo[p * 40 + dc + j] = f2b(kf[j] - b2f(khi));
            u16 vhi = f2b(vf[j]);
            vp_hi[(dc + j) * 72 + p] = vhi;
            vp_lo[(dc + j) * 72 + p] = f2b(vf[j] - b2f(vhi));
        }
    }
    for (int t = tid; t < 512; t += 256) {
        int l = t & 15, d = t >> 4;
        ltb[l * 32 + d] = (l < 9) ? f2b(lt[h * 288 + d * 9 + l]) : (u16)0;
    }
    if (tid < 9) { rpb_s[tid] = rpb[h * 9 + tid]; lb_s[tid] = lb[h * 9 + tid]; }
    __syncthreads();

    // ---- step 1: load q, build A-fragments ----
    int n0w = tile * 64 + wave * 16;
    float tsc = log1pf(expf(temp[h]));
    bf16x8 qs_hi, qs_lo, qn_b;
    {
        int n = n0w + l16;
        const float* qptr = qn + ((size_t)(b * N_ + n)) * C_ + h * 32 + quad * 8;
        float4 q0 = *(const float4*)qptr, q1 = *(const float4*)(qptr + 4);
        const float* qeptr = qe + h * 32 + quad * 8;
        float4 e0 = *(const float4*)qeptr, e1 = *(const float4*)(qeptr + 4);
        float slv = slsin[n];
        float qf[8] = {q0.x,q0.y,q0.z,q0.w,q1.x,q1.y,q1.z,q1.w};
        float ef[8] = {e0.x,e0.y,e0.z,e0.w,e1.x,e1.y,e1.z,e1.w};
        #pragma unroll
        for (int j = 0; j < 8; ++j) {
            float qs = (qf[j] + ef[j]) * tsc * slv;
            u16 hi = f2b(qs);
            qs_hi[j] = (short)hi;
            qs_lo[j] = f2bs(qs - b2f(hi));
            qn_b[j]  = f2bs(qf[j]);
            qs_w[wave][l16][quad * 8 + j] = qs;
        }
        if (quad == 0) { S_w[wave][l16][73] = NEG_; S_w[wave][l16][74] = NEG_; S_w[wave][l16][75] = NEG_; }
    }

    // ---- step 2: pool logits (12 MFMA, compensated) + bias gather ----
    #pragma unroll
    for (int jt = 0; jt < 4; ++jt) {
        bf16x8 bh = *(const bf16x8*)&kp_hi[(jt * 16 + l16) * 40 + quad * 8];
        bf16x8 bl = *(const bf16x8*)&kp_lo[(jt * 16 + l16) * 40 + quad * 8];
        f32x4 a = {};
        a = __builtin_amdgcn_mfma_f32_16x16x32_bf16(qs_lo, bh, a, 0, 0, 0);
        a = __builtin_amdgcn_mfma_f32_16x16x32_bf16(qs_hi, bl, a, 0, 0, 0);
        a = __builtin_amdgcn_mfma_f32_16x16x32_bf16(qs_hi, bh, a, 0, 0, 0);
        #pragma unroll
        for (int r = 0; r < 4; ++r) {
            int pix = quad * 4 + r;
            int n = n0w + pix;
            int idx = rpi[n * P_ + jt * 16 + l16];
            S_w[wave][pix][jt * 16 + l16] = a[r] + cpb[(size_t)idx * 8 + h];
        }
    }
    // ---- learnable-token logits (1 MFMA) ----
    f32x4 accL;
    {
        bf16x8 ltf = *(const bf16x8*)&ltb[l16 * 32 + quad * 8];
        f32x4 z = {};
        accL = __builtin_amdgcn_mfma_f32_16x16x32_bf16(qn_b, ltf, z, 0, 0, 0);
    }
    // ---- step 3: local 3x3 logits (fp32 VALU) ----
    for (int t = lane; t < 144; t += 64) {
        int pix = t / 9, l = t - pix * 9;
        int n = n0w + pix, y = n >> 6, x = n & 63;
        int ny = y + l / 3 - 1, nx = x + (l % 3) - 1;
        bool ok = ((unsigned)ny < 64u) && ((unsigned)nx < 64u);
        int nn = ok ? ny * 64 + nx : n;
        const float4* kb = (const float4*)(kv + ((size_t)(b * N_ + nn)) * 512 + h * 32);
        float acl = 0.0f;
        #pragma unroll
        for (int d4 = 0; d4 < 8; ++d4) {
            float4 kk = kb[d4];
            float4 qq = *(const float4*)&qs_w[wave][pix][d4 * 4];
            acl += qq.x * kk.x + qq.y * kk.y + qq.z * kk.z + qq.w * kk.w;
        }
        S_w[wave][pix][64 + l] = ok ? (acl + rpb_s[l]) : NEG_;
    }
    // ---- step 4: softmax over 73 (4 lanes per pixel, 19 cols each) ----
    {
        int pix = lane >> 2, c0 = (lane & 3) * 19;
        float vals[19]; float mx = NEG_;
        #pragma unroll
        for (int i = 0; i < 19; ++i) { vals[i] = S_w[wave][pix][c0 + i]; mx = fmaxf(mx, vals[i]); }
        mx = fmaxf(mx, __shfl_xor(mx, 1));
        mx = fmaxf(mx, __shfl_xor(mx, 2));
        float sm = 0.0f;
        #pragma unroll
        for (int i = 0; i < 19; ++i) { vals[i] = expf(vals[i] - mx); sm += vals[i]; }
        sm += __shfl_xor(sm, 1); sm += __shfl_xor(sm, 2);
        float inv = 1.0f / sm;
        #pragma unroll
        for (int i = 0; i < 19; ++i) S_w[wave][pix][c0 + i] = vals[i] * inv;
    }
    // ---- step 4b: combined local weights a = lt_dot + lb + softmaxed-local -> cols 76..84 ----
    if (l16 < 9) {
        #pragma unroll
        for (int r = 0; r < 4; ++r) {
            int pix = quad * 4 + r;
            int n = n0w + pix, y = n >> 6, x = n & 63;
            int ny = y + l16 / 3 - 1, nx = x + (l16 % 3) - 1;
            bool ok = ((unsigned)ny < 64u) && ((unsigned)nx < 64u);
            S_w[wave][pix][76 + l16] = ok ? (accL[r] + lb_s[l16] + S_w[wave][pix][64 + l16]) : 0.0f;
        }
    }
    // ---- step 5: PV (12 MFMA, compensated) + local-V (fp32 VALU) ----
    f32x4 accO[2] = {};
    #pragma unroll
    for (int kc = 0; kc < 2; ++kc) {
        float wf[8];
        *(float4*)&wf[0] = *(const float4*)&S_w[wave][l16][kc * 32 + quad * 8];
        *(float4*)&wf[4] = *(const float4*)&S_w[wave][l16][kc * 32 + quad * 8 + 4];
        bf16x8 w_hi, w_lo;
        #pragma unroll
        for (int j = 0; j < 8; ++j) {
            u16 hi = f2b(wf[j]);
            w_hi[j] = (short)hi;
            w_lo[j] = f2bs(wf[j] - b2f(hi));
        }
        #pragma unroll
        for (int nt = 0; nt < 2; ++nt) {
            bf16x8 vh = *(const bf16x8*)&vp_hi[(nt * 16 + l16) * 72 + kc * 32 + quad * 8];
            bf16x8 vl = *(const bf16x8*)&vp_lo[(nt * 16 + l16) * 72 + kc * 32 + quad * 8];
            accO[nt] = __builtin_amdgcn_mfma_f32_16x16x32_bf16(w_lo, vh, accO[nt], 0, 0, 0);
            accO[nt] = __builtin_amdgcn_mfma_f32_16x16x32_bf16(w_hi, vl, accO[nt], 0, 0, 0);
            accO[nt] = __builtin_amdgcn_mfma_f32_16x16x32_bf16(w_hi, vh, accO[nt], 0, 0, 0);
        }
    }
    #pragma unroll
    for (int r = 0; r < 4; ++r) {
        int pix = quad * 4 + r;
        int n = n0w + pix, y = n >> 6, x = n & 63;
        #pragma unroll
        for (int l = 0; l < 9; ++l) {
            int ny = y + l / 3 - 1, nx = x + (l % 3) - 1;
            bool ok = ((unsigned)ny < 64u) && ((unsigned)nx < 64u);
            int nn = ok ? ny * 64 + nx : n;
            float aw = S_w[wave][pix][76 + l];
            const float* vb = kv + ((size_t)(b * N_ + nn)) * 512 + 256 + h * 32;
            accO[0][r] += aw * vb[l16];
            accO[1][r] += aw * vb[16 + l16];
        }
    }
    #pragma unroll
    for (int nt = 0; nt < 2; ++nt)
        #pragma unroll
        for (int r = 0; r < 4; ++r) {
            int n = n0w + quad * 4 + r;
            aob[((size_t)(b * N_ + n)) * C_ + h * 32 + nt * 16 + l16] = f2b(accO[nt][r]);
        }
}

extern "C" void kernel_launch(void* const* d_in, const int* in_sizes, int n_in,
                              void* d_out, int out_size, void* d_ws, size_t ws_size,
                              hipStream_t stream) {
    const float* x      = (const float*)d_in[0];
    const int*   rpi    = (const int*)d_in[1];
    const float* table  = (const float*)d_in[2];
    const float* q_w    = (const float*)d_in[3];
    const float* q_b    = (const float*)d_in[4];
    const float* kv_w   = (const float*)d_in[5];
    const float* kv_b   = (const float*)d_in[6];
    const float* temp   = (const float*)d_in[7];
    const float* qe     = (const float*)d_in[8];
    const float* proj_w = (const float*)d_in[9];
    const float* proj_b = (const float*)d_in[10];
    const float* sr_w   = (const float*)d_in[11];
    const float* sr_b   = (const float*)d_in[12];
    const float* norm_g = (const float*)d_in[13];
    const float* norm_b = (const float*)d_in[14];
    const float* cpb1_w = (const float*)d_in[15];
    const float* cpb1_b = (const float*)d_in[16];
    const float* cpb2_w = (const float*)d_in[17];
    const float* cpb2_b = (const float*)d_in[18];
    const float* rpb    = (const float*)d_in[19];
    const float* lt     = (const float*)d_in[20];
    const float* lb     = (const float*)d_in[21];
    const float* sls    = (const float*)d_in[22];

    float* ws  = (float*)d_ws;
    float* qn  = ws;                                  // B*N*C fp32 (l2normed in GEMM epilogue)
    float* kv  = qn  + (size_t)B_ * N_ * C_;          // B*N*2C fp32 (k-part l2normed)
    float* xg  = kv  + (size_t)B_ * N_ * 2 * C_;      // B*N*C fp32 (reused as bf16 attn out)
    float* xp  = xg  + (size_t)B_ * N_ * C_;          // B*P*C fp32
    float* kvp = xp  + (size_t)B_ * P_ * C_;          // B*P*2C fp32
    float* cpb = kvp + (size_t)B_ * P_ * 2 * C_;      // T*NH fp32
    u16*   qwb = (u16*)(cpb + (size_t)T_ * NH_);      // C*C bf16
    u16*   kwb = qwb + (size_t)C_ * C_;               // 2C*C bf16
    u16*   swb = kwb + (size_t)2 * C_ * C_;           // C*C bf16
    u16*   pwb = swb + (size_t)C_ * C_;               // C*C bf16
    u16*   aob = (u16*)xg;                            // B*N*C bf16 (xg dead after pool_ln)

    const int M = B_ * N_;
    dim3 blk(256);

    // weight conversions (one launch)
    cvtw_k<<<dim3(320), blk, 0, stream>>>(q_w, kv_w, sr_w, proj_w, qwb, kwb, swb, pwb);

    // q = l2norm_heads(x @ q_w^T + q_b)   [fused norm]
    gemm_mfma_k<0, 1, 1><<<dim3(C_ / 64, M / 64), blk, 0, stream>>>(x, qwb, q_b, qn, C_, C_);
    // kv = x @ kv_w^T + kv_b ; k-part l2normed  [fused norm]
    gemm_mfma_k<0, 2, 1><<<dim3(2 * C_ / 64, M / 64), blk, 0, stream>>>(x, kwb, kv_b, kv, 2 * C_, C_);
    // xg = gelu(x @ sr_w^T + sr_b)
    gemm_mfma_k<1, 0, 1><<<dim3(C_ / 64, M / 64), blk, 0, stream>>>(x, swb, sr_b, xg, C_, C_);
    pool_ln_k<<<dim3(B_ * P_), blk, 0, stream>>>(xg, norm_g, norm_b, xp);
    // kv_pool = x_pool @ kv_w^T + kv_b ; normalize k part (small, fp32)
    gemm_f32_k<<<dim3(2 * C_ / 64, (B_ * P_) / 64), blk, 0, stream>>>(xp, kv_w, kv_b, kvp, 2 * C_, C_);
    l2norm_heads_k<<<dim3(B_ * P_), blk, 0, stream>>>(kvp, 2 * C_);
    // cpb table
    cpb_k<<<dim3(T_ / 256), blk, 0, stream>>>(table, cpb1_w, cpb1_b, cpb2_w, cpb2_b, cpb);
    // fused MFMA attention -> aob (bf16)
    attn_k<<<dim3(B_ * NH_ * 64), blk, 0, stream>>>(qn, kv, kvp, cpb, rpi, temp, qe, lt, rpb, lb, sls, aob);
    // out = aob @ proj_w^T + proj_b (fp32 out)
    gemm_mfma_k<0, 0, 0><<<dim3(C_ / 64, M / 64), blk, 0, stream>>>(aob, pwb, proj_b, (float*)d_out, C_, C_);
}

// Round 6
// 293.883 us; speedup vs baseline: 3.4872x; 1.2395x over previous
//
#include <hip/hip_runtime.h>
#include <hip/hip_bf16.h>

typedef unsigned short u16;
typedef unsigned int u32;

#define B_ 4
#define N_ 4096
#define C_ 256
#define NH_ 8
#define HD_ 32
#define L_ 9
#define P_ 64
#define T_ 4096
#define NEG_ (-1e30f)

typedef __attribute__((ext_vector_type(8))) short bf16x8;
typedef __attribute__((ext_vector_type(4))) float f32x4;

__device__ __forceinline__ float b2f(u16 u) {
    union { u32 i; float f; } v; v.i = ((u32)u) << 16; return v.f;
}
__device__ __forceinline__ u16 f2b(float f) {
    u32 x = __float_as_uint(f);
    u32 r = (x + 0x7fffu + ((x >> 16) & 1u)) >> 16;
    return (u16)r;
}
__device__ __forceinline__ short f2bs(float f) { return (short)f2b(f); }

// ---------------- prep: x->bf16, weights->bf16 (fused W), CPB MLP — one launch ----------------
// blocks [0,4096): x convert; [4096,4416): weight convert; [4416,4432): cpb
__global__ __launch_bounds__(256) void prep_k(
    const float* __restrict__ x, const float* __restrict__ q_w, const float* __restrict__ kv_w,
    const float* __restrict__ sr_w, const float* __restrict__ proj_w,
    u16* __restrict__ xb, u16* __restrict__ wfused, u16* __restrict__ pwb,
    const float* __restrict__ table, const float* __restrict__ w1, const float* __restrict__ b1,
    const float* __restrict__ w2, const float* __restrict__ b2, float* __restrict__ cpb)
{
    __shared__ float w1s[512][2];
    __shared__ float b1s[512];
    __shared__ float w2s[8][512];
    int bid = blockIdx.x, tid = threadIdx.x;
    if (bid < 4096) {
        int i = bid * 256 + tid;              // 1,048,576 float4
        float4 v = reinterpret_cast<const float4*>(x)[i];
        ushort4 o; o.x = f2b(v.x); o.y = f2b(v.y); o.z = f2b(v.z); o.w = f2b(v.w);
        reinterpret_cast<ushort4*>(xb)[i] = o;
    } else if (bid < 4416) {
        int i = (bid - 4096) * 256 + tid;     // 81,920 float4
        const float* s; u16* d; int off;
        if (i < 16384)      { s = q_w;    d = wfused; off = i; }
        else if (i < 49152) { s = kv_w;   d = wfused; off = i; }          // contiguous rows
        else if (i < 65536) { s = sr_w;   d = wfused; off = i; }
        else                { s = proj_w; d = pwb;    off = i - 65536; }
        // source offset within its own matrix:
        int soff = (i < 16384) ? i : (i < 49152) ? (i - 16384) : (i < 65536) ? (i - 49152) : (i - 65536);
        float4 v = reinterpret_cast<const float4*>(s)[soff];
        ushort4 o; o.x = f2b(v.x); o.y = f2b(v.y); o.z = f2b(v.z); o.w = f2b(v.w);
        reinterpret_cast<ushort4*>(d)[off] = o;
    } else {
        for (int i = tid; i < 512; i += 256) {
            w1s[i][0] = w1[i * 2]; w1s[i][1] = w1[i * 2 + 1]; b1s[i] = b1[i];
        }
        for (int i = tid; i < 4096; i += 256) w2s[i >> 9][i & 511] = w2[i];
        __syncthreads();
        int t = (bid - 4416) * 256 + tid;
        float t0 = table[t * 2], t1 = table[t * 2 + 1];
        float acc[8] = {};
        for (int j = 0; j < 512; ++j) {
            float h = fmaxf(t0 * w1s[j][0] + t1 * w1s[j][1] + b1s[j], 0.0f);
            #pragma unroll
            for (int hh = 0; hh < 8; ++hh) acc[hh] += h * w2s[hh][j];
        }
        #pragma unroll
        for (int hh = 0; hh < 8; ++hh) cpb[t * 8 + hh] = acc[hh] + b2[hh];
    }
}

// ---------------- big MFMA GEMM, tile 128x128, wave 64x64, no LDS ----------------
// MODE 0: fused q/kv/sr (N=1024, grid.x=8), per-range epilogue (norm / norm / plain / gelu-bf16)
// MODE 1: proj (N=256, grid.x=2), plain fp32 store to pout
template<int MODE>
__global__ __launch_bounds__(256) void gemm_big_k(
    const u16* __restrict__ A, const u16* __restrict__ W,
    const float* __restrict__ b0, const float* __restrict__ b1, const float* __restrict__ b2,
    float* __restrict__ qn, float* __restrict__ kv, u16* __restrict__ xgb, float* __restrict__ pout)
{
    const int K = 256;
    int tid = threadIdx.x, w = tid >> 6, lane = tid & 63;
    int quad = lane >> 4, l16 = lane & 15;
    int wr = w >> 1, wc = w & 1;
    int rowBase = blockIdx.y * 128 + wr * 64;
    int colBase = blockIdx.x * 128 + wc * 64;
    f32x4 acc[4][4] = {};
    const u16* aptr = A + (size_t)(rowBase + l16) * K + quad * 8;
    const u16* wptr = W + (size_t)(colBase + l16) * K + quad * 8;
    for (int k0 = 0; k0 < K; k0 += 32) {
        bf16x8 af[4], bfr[4];
        #pragma unroll
        for (int i = 0; i < 4; ++i) af[i] = *reinterpret_cast<const bf16x8*>(aptr + (size_t)i * 16 * K + k0);
        #pragma unroll
        for (int j = 0; j < 4; ++j) bfr[j] = *reinterpret_cast<const bf16x8*>(wptr + (size_t)j * 16 * K + k0);
        #pragma unroll
        for (int i = 0; i < 4; ++i)
            #pragma unroll
            for (int j = 0; j < 4; ++j)
                acc[i][j] = __builtin_amdgcn_mfma_f32_16x16x32_bf16(af[i], bfr[j], acc[i][j], 0, 0, 0);
    }
    int rng = (MODE == 0) ? (colBase >> 8) : 99;   // 0:q 1:kv-k 2:kv-v 3:sr
    float bj[4];
    #pragma unroll
    for (int j = 0; j < 4; ++j) {
        int gc = colBase + j * 16 + l16;
        if (MODE == 1)      bj[j] = b0[gc];
        else if (rng == 0)  bj[j] = b0[gc];
        else if (rng <= 2)  bj[j] = b1[gc - 256];
        else                bj[j] = b2[gc - 768];
    }
    #pragma unroll
    for (int i = 0; i < 4; ++i) {
        float vals[4][4];
        #pragma unroll
        for (int j = 0; j < 4; ++j)
            #pragma unroll
            for (int r = 0; r < 4; ++r) {
                float t = acc[i][j][r] + bj[j];
                if (MODE == 0 && rng == 3) t = 0.5f * t * (1.0f + erff(t * 0.70710678118654752f));
                vals[j][r] = t;
            }
        if (MODE == 0 && rng <= 1) {
            #pragma unroll
            for (int hp = 0; hp < 2; ++hp)
                #pragma unroll
                for (int r = 0; r < 4; ++r) {
                    float s = vals[2*hp][r] * vals[2*hp][r] + vals[2*hp+1][r] * vals[2*hp+1][r];
                    s += __shfl_xor(s, 1); s += __shfl_xor(s, 2);
                    s += __shfl_xor(s, 4); s += __shfl_xor(s, 8);
                    float inv = 1.0f / fmaxf(sqrtf(s), 1e-12f);
                    vals[2*hp][r] *= inv; vals[2*hp+1][r] *= inv;
                }
        }
        #pragma unroll
        for (int j = 0; j < 4; ++j) {
            int gc = colBase + j * 16 + l16;
            #pragma unroll
            for (int r = 0; r < 4; ++r) {
                int row = rowBase + i * 16 + quad * 4 + r;
                if (MODE == 1)      pout[(size_t)row * 256 + gc] = vals[j][r];
                else if (rng == 0)  qn[(size_t)row * 256 + gc] = vals[j][r];
                else if (rng <= 2)  kv[(size_t)row * 512 + gc - 256] = vals[j][r];
                else                xgb[(size_t)row * 256 + gc - 768] = f2b(vals[j][r]);
            }
        }
    }
}

// ---------------- fused avgpool + LayerNorm + kv_pool GEMM + k-norm: one block per (b,p) ----------------
__global__ __launch_bounds__(256) void poolkv_k(
    const u16* __restrict__ xgb, const float* __restrict__ g, const float* __restrict__ bta,
    const float* __restrict__ kv_w, const float* __restrict__ kv_b, float* __restrict__ kvp)
{
    __shared__ __align__(16) float xps[256];
    __shared__ float r1[4], r2[4];
    int bp = blockIdx.x;
    int b = bp >> 6, p = bp & 63;
    int py = p >> 3, px = p & 7;
    int o = threadIdx.x;
    float s = 0.0f;
    for (int sy = 0; sy < 8; ++sy)
        #pragma unroll
        for (int sx = 0; sx < 8; ++sx) {
            int pix = (py * 8 + sy) * 64 + px * 8 + sx;
            s += b2f(xgb[((size_t)(b * N_ + pix)) * C_ + o]);
        }
    float v = s * (1.0f / 64.0f);
    float s1 = v, s2 = v * v;
    #pragma unroll
    for (int off = 32; off >= 1; off >>= 1) { s1 += __shfl_xor(s1, off); s2 += __shfl_xor(s2, off); }
    int wv = o >> 6, ln = o & 63;
    if (ln == 0) { r1[wv] = s1; r2[wv] = s2; }
    __syncthreads();
    float S1 = r1[0] + r1[1] + r1[2] + r1[3];
    float S2 = r2[0] + r2[1] + r2[2] + r2[3];
    float mu = S1 * (1.0f / 256.0f);
    float var = S2 * (1.0f / 256.0f) - mu * mu;
    xps[o] = (v - mu) * rsqrtf(var + 1e-5f) * g[o] + bta[o];
    __syncthreads();
    // kv_pool row (b,p): cols o (k-part) and o+256 (v-part)
    float a0 = kv_b[o], a1 = kv_b[o + 256];
    const float4* xp4 = (const float4*)xps;
    const float4* w0 = (const float4*)(kv_w + (size_t)o * 256);
    const float4* w1 = (const float4*)(kv_w + (size_t)(o + 256) * 256);
    #pragma unroll 4
    for (int k4 = 0; k4 < 64; ++k4) {
        float4 xv = xp4[k4]; float4 wa = w0[k4]; float4 wb = w1[k4];
        a0 += xv.x * wa.x + xv.y * wa.y + xv.z * wa.z + xv.w * wa.w;
        a1 += xv.x * wb.x + xv.y * wb.y + xv.z * wb.z + xv.w * wb.w;
    }
    // l2norm the k-part per 32-col head (lanes o..o+31 in same wave half)
    float ss = a0 * a0;
    ss += __shfl_xor(ss, 1); ss += __shfl_xor(ss, 2); ss += __shfl_xor(ss, 4);
    ss += __shfl_xor(ss, 8); ss += __shfl_xor(ss, 16);
    a0 *= 1.0f / fmaxf(sqrtf(ss), 1e-12f);
    kvp[(size_t)bp * 512 + o] = a0;
    kvp[(size_t)bp * 512 + 256 + o] = a1;
}

// ---------------- MFMA fused attention (unchanged from R5) ----------------
__global__ __launch_bounds__(256) void attn_k(
    const float* __restrict__ qn, const float* __restrict__ kv,
    const float* __restrict__ kvp, const float* __restrict__ cpb,
    const int* __restrict__ rpi, const float* __restrict__ temp,
    const float* __restrict__ qe, const float* __restrict__ lt,
    const float* __restrict__ rpb, const float* __restrict__ lb,
    const float* __restrict__ slsin, u16* __restrict__ aob)
{
    __shared__ u16 kp_hi[64 * 40], kp_lo[64 * 40];
    __shared__ u16 vp_hi[32 * 72], vp_lo[32 * 72];
    __shared__ u16 ltb[16 * 32];
    __shared__ float qs_w[4][16][36];
    __shared__ float S_w[4][16][88];
    __shared__ float rpb_s[9], lb_s[9];

    int bid = blockIdx.x;
    int tile = bid & 63, h = (bid >> 6) & 7, b = bid >> 9;
    int tid = threadIdx.x, wave = tid >> 6, lane = tid & 63;
    int quad = lane >> 4, l16 = lane & 15;

    {
        int p = tid >> 2, dc = (tid & 3) * 8;
        const float* src = kvp + ((size_t)(b * P_ + p)) * 512 + h * 32 + dc;
        float4 k0 = *(const float4*)(src), k1 = *(const float4*)(src + 4);
        float4 v0 = *(const float4*)(src + 256), v1 = *(const float4*)(src + 260);
        float kf[8] = {k0.x,k0.y,k0.z,k0.w,k1.x,k1.y,k1.z,k1.w};
        float vf[8] = {v0.x,v0.y,v0.z,v0.w,v1.x,v1.y,v1.z,v1.w};
        #pragma unroll
        for (int j = 0; j < 8; ++j) {
            u16 khi = f2b(kf[j]);
            kp_hi[p * 40 + dc + j] = khi;
            kp_lo[p * 40 + dc + j] = f2b(kf[j] - b2f(khi));
            u16 vhi = f2b(vf[j]);
            vp_hi[(dc + j) * 72 + p] = vhi;
            vp_lo[(dc + j) * 72 + p] = f2b(vf[j] - b2f(vhi));
        }
    }
    for (int t = tid; t < 512; t += 256) {
        int l = t & 15, d = t >> 4;
        ltb[l * 32 + d] = (l < 9) ? f2b(lt[h * 288 + d * 9 + l]) : (u16)0;
    }
    if (tid < 9) { rpb_s[tid] = rpb[h * 9 + tid]; lb_s[tid] = lb[h * 9 + tid]; }
    __syncthreads();

    int n0w = tile * 64 + wave * 16;
    float tsc = log1pf(expf(temp[h]));
    bf16x8 qs_hi, qs_lo, qn_b;
    {
        int n = n0w + l16;
        const float* qptr = qn + ((size_t)(b * N_ + n)) * C_ + h * 32 + quad * 8;
        float4 q0 = *(const float4*)qptr, q1 = *(const float4*)(qptr + 4);
        const float* qeptr = qe + h * 32 + quad * 8;
        float4 e0 = *(const float4*)qeptr, e1 = *(const float4*)(qeptr + 4);
        float slv = slsin[n];
        float qf[8] = {q0.x,q0.y,q0.z,q0.w,q1.x,q1.y,q1.z,q1.w};
        float ef[8] = {e0.x,e0.y,e0.z,e0.w,e1.x,e1.y,e1.z,e1.w};
        #pragma unroll
        for (int j = 0; j < 8; ++j) {
            float qs = (qf[j] + ef[j]) * tsc * slv;
            u16 hi = f2b(qs);
            qs_hi[j] = (short)hi;
            qs_lo[j] = f2bs(qs - b2f(hi));
            qn_b[j]  = f2bs(qf[j]);
            qs_w[wave][l16][quad * 8 + j] = qs;
        }
        if (quad == 0) { S_w[wave][l16][73] = NEG_; S_w[wave][l16][74] = NEG_; S_w[wave][l16][75] = NEG_; }
    }

    #pragma unroll
    for (int jt = 0; jt < 4; ++jt) {
        bf16x8 bh = *(const bf16x8*)&kp_hi[(jt * 16 + l16) * 40 + quad * 8];
        bf16x8 bl = *(const bf16x8*)&kp_lo[(jt * 16 + l16) * 40 + quad * 8];
        f32x4 a = {};
        a = __builtin_amdgcn_mfma_f32_16x16x32_bf16(qs_lo, bh, a, 0, 0, 0);
        a = __builtin_amdgcn_mfma_f32_16x16x32_bf16(qs_hi, bl, a, 0, 0, 0);
        a = __builtin_amdgcn_mfma_f32_16x16x32_bf16(qs_hi, bh, a, 0, 0, 0);
        #pragma unroll
        for (int r = 0; r < 4; ++r) {
            int pix = quad * 4 + r;
            int n = n0w + pix;
            int idx = rpi[n * P_ + jt * 16 + l16];
            S_w[wave][pix][jt * 16 + l16] = a[r] + cpb[(size_t)idx * 8 + h];
        }
    }
    f32x4 accL;
    {
        bf16x8 ltf = *(const bf16x8*)&ltb[l16 * 32 + quad * 8];
        f32x4 z = {};
        accL = __builtin_amdgcn_mfma_f32_16x16x32_bf16(qn_b, ltf, z, 0, 0, 0);
    }
    for (int t = lane; t < 144; t += 64) {
        int pix = t / 9, l = t - pix * 9;
        int n = n0w + pix, y = n >> 6, x = n & 63;
        int ny = y + l / 3 - 1, nx = x + (l % 3) - 1;
        bool ok = ((unsigned)ny < 64u) && ((unsigned)nx < 64u);
        int nn = ok ? ny * 64 + nx : n;
        const float4* kb = (const float4*)(kv + ((size_t)(b * N_ + nn)) * 512 + h * 32);
        float acl = 0.0f;
        #pragma unroll
        for (int d4 = 0; d4 < 8; ++d4) {
            float4 kk = kb[d4];
            float4 qq = *(const float4*)&qs_w[wave][pix][d4 * 4];
            acl += qq.x * kk.x + qq.y * kk.y + qq.z * kk.z + qq.w * kk.w;
        }
        S_w[wave][pix][64 + l] = ok ? (acl + rpb_s[l]) : NEG_;
    }
    {
        int pix = lane >> 2, c0 = (lane & 3) * 19;
        float vals[19]; float mx = NEG_;
        #pragma unroll
        for (int i = 0; i < 19; ++i) { vals[i] = S_w[wave][pix][c0 + i]; mx = fmaxf(mx, vals[i]); }
        mx = fmaxf(mx, __shfl_xor(mx, 1));
        mx = fmaxf(mx, __shfl_xor(mx, 2));
        float sm = 0.0f;
        #pragma unroll
        for (int i = 0; i < 19; ++i) { vals[i] = expf(vals[i] - mx); sm += vals[i]; }
        sm += __shfl_xor(sm, 1); sm += __shfl_xor(sm, 2);
        float inv = 1.0f / sm;
        #pragma unroll
        for (int i = 0; i < 19; ++i) S_w[wave][pix][c0 + i] = vals[i] * inv;
    }
    if (l16 < 9) {
        #pragma unroll
        for (int r = 0; r < 4; ++r) {
            int pix = quad * 4 + r;
            int n = n0w + pix, y = n >> 6, x = n & 63;
            int ny = y + l16 / 3 - 1, nx = x + (l16 % 3) - 1;
            bool ok = ((unsigned)ny < 64u) && ((unsigned)nx < 64u);
            S_w[wave][pix][76 + l16] = ok ? (accL[r] + lb_s[l16] + S_w[wave][pix][64 + l16]) : 0.0f;
        }
    }
    f32x4 accO[2] = {};
    #pragma unroll
    for (int kc = 0; kc < 2; ++kc) {
        float wf[8];
        *(float4*)&wf[0] = *(const float4*)&S_w[wave][l16][kc * 32 + quad * 8];
        *(float4*)&wf[4] = *(const float4*)&S_w[wave][l16][kc * 32 + quad * 8 + 4];
        bf16x8 w_hi, w_lo;
        #pragma unroll
        for (int j = 0; j < 8; ++j) {
            u16 hi = f2b(wf[j]);
            w_hi[j] = (short)hi;
            w_lo[j] = f2bs(wf[j] - b2f(hi));
        }
        #pragma unroll
        for (int nt = 0; nt < 2; ++nt) {
            bf16x8 vh = *(const bf16x8*)&vp_hi[(nt * 16 + l16) * 72 + kc * 32 + quad * 8];
            bf16x8 vl = *(const bf16x8*)&vp_lo[(nt * 16 + l16) * 72 + kc * 32 + quad * 8];
            accO[nt] = __builtin_amdgcn_mfma_f32_16x16x32_bf16(w_lo, vh, accO[nt], 0, 0, 0);
            accO[nt] = __builtin_amdgcn_mfma_f32_16x16x32_bf16(w_hi, vl, accO[nt], 0, 0, 0);
            accO[nt] = __builtin_amdgcn_mfma_f32_16x16x32_bf16(w_hi, vh, accO[nt], 0, 0, 0);
        }
    }
    #pragma unroll
    for (int r = 0; r < 4; ++r) {
        int pix = quad * 4 + r;
        int n = n0w + pix, y = n >> 6, x = n & 63;
        #pragma unroll
        for (int l = 0; l < 9; ++l) {
            int ny = y + l / 3 - 1, nx = x + (l % 3) - 1;
            bool ok = ((unsigned)ny < 64u) && ((unsigned)nx < 64u);
            int nn = ok ? ny * 64 + nx : n;
            float aw = S_w[wave][pix][76 + l];
            const float* vb = kv + ((size_t)(b * N_ + nn)) * 512 + 256 + h * 32;
            accO[0][r] += aw * vb[l16];
            accO[1][r] += aw * vb[16 + l16];
        }
    }
    #pragma unroll
    for (int nt = 0; nt < 2; ++nt)
        #pragma unroll
        for (int r = 0; r < 4; ++r) {
            int n = n0w + quad * 4 + r;
            aob[((size_t)(b * N_ + n)) * C_ + h * 32 + nt * 16 + l16] = f2b(accO[nt][r]);
        }
}

extern "C" void kernel_launch(void* const* d_in, const int* in_sizes, int n_in,
                              void* d_out, int out_size, void* d_ws, size_t ws_size,
                              hipStream_t stream) {
    const float* x      = (const float*)d_in[0];
    const int*   rpi    = (const int*)d_in[1];
    const float* table  = (const float*)d_in[2];
    const float* q_w    = (const float*)d_in[3];
    const float* q_b    = (const float*)d_in[4];
    const float* kv_w   = (const float*)d_in[5];
    const float* kv_b   = (const float*)d_in[6];
    const float* temp   = (const float*)d_in[7];
    const float* qe     = (const float*)d_in[8];
    const float* proj_w = (const float*)d_in[9];
    const float* proj_b = (const float*)d_in[10];
    const float* sr_w   = (const float*)d_in[11];
    const float* sr_b   = (const float*)d_in[12];
    const float* norm_g = (const float*)d_in[13];
    const float* norm_b = (const float*)d_in[14];
    const float* cpb1_w = (const float*)d_in[15];
    const float* cpb1_b = (const float*)d_in[16];
    const float* cpb2_w = (const float*)d_in[17];
    const float* cpb2_b = (const float*)d_in[18];
    const float* rpb    = (const float*)d_in[19];
    const float* lt     = (const float*)d_in[20];
    const float* lb     = (const float*)d_in[21];
    const float* sls    = (const float*)d_in[22];

    float* ws  = (float*)d_ws;
    float* qn  = ws;                                   // B*N*C fp32
    float* kv  = qn  + (size_t)B_ * N_ * C_;           // B*N*2C fp32
    float* kvp = kv  + (size_t)B_ * N_ * 2 * C_;       // B*P*2C fp32
    float* cpb = kvp + (size_t)B_ * P_ * 2 * C_;       // T*NH fp32
    u16*   xb  = (u16*)(cpb + (size_t)T_ * NH_);       // B*N*C bf16
    u16*   wfb = xb  + (size_t)B_ * N_ * C_;           // 1024*256 bf16 (q;kv;sr)
    u16*   pwb = wfb + (size_t)1024 * C_;              // C*C bf16
    u16*   xgb = pwb + (size_t)C_ * C_;                // B*N*C bf16 (gelu out; reused as attn out)
    u16*   aob = xgb;                                  // alias: xgb consumed by poolkv before attn writes

    dim3 blk(256);

    // 1) prep: x->bf16, weights->bf16, cpb table
    prep_k<<<dim3(4432), blk, 0, stream>>>(x, q_w, kv_w, sr_w, proj_w, xb, wfb, pwb,
                                           table, cpb1_w, cpb1_b, cpb2_w, cpb2_b, cpb);
    // 2) fused GEMM: qn (l2norm), kv (k l2norm), xgb (gelu bf16)
    gemm_big_k<0><<<dim3(8, 128), blk, 0, stream>>>(xb, wfb, q_b, kv_b, sr_b, qn, kv, xgb, nullptr);
    // 3) pool + LN + kv_pool + k-norm
    poolkv_k<<<dim3(B_ * P_), blk, 0, stream>>>(xgb, norm_g, norm_b, kv_w, kv_b, kvp);
    // 4) fused MFMA attention -> aob (bf16)
    attn_k<<<dim3(B_ * NH_ * 64), blk, 0, stream>>>(qn, kv, kvp, cpb, rpi, temp, qe, lt, rpb, lb, sls, aob);
    // 5) proj -> d_out (fp32)
    gemm_big_k<1><<<dim3(2, 128), blk, 0, stream>>>(aob, pwb, proj_b, nullptr, nullptr,
                                                    nullptr, nullptr, nullptr, (float*)d_out);
}

// Round 7
// 277.446 us; speedup vs baseline: 3.6938x; 1.0592x over previous
//
#include <hip/hip_runtime.h>
#include <hip/hip_bf16.h>

typedef unsigned short u16;
typedef unsigned int u32;

#define B_ 4
#define N_ 4096
#define C_ 256
#define NH_ 8
#define HD_ 32
#define L_ 9
#define P_ 64
#define T_ 4096
#define NEG_ (-1e30f)

typedef __attribute__((ext_vector_type(8))) short bf16x8;
typedef __attribute__((ext_vector_type(4))) float f32x4;

__device__ __forceinline__ float b2f(u16 u) {
    union { u32 i; float f; } v; v.i = ((u32)u) << 16; return v.f;
}
__device__ __forceinline__ u16 f2b(float f) {
    u32 x = __float_as_uint(f);
    u32 r = (x + 0x7fffu + ((x >> 16) & 1u)) >> 16;
    return (u16)r;
}
__device__ __forceinline__ short f2bs(float f) { return (short)f2b(f); }

// ---------------- prep: x->bf16, weights->bf16 (fused W), CPB MLP — one launch ----------------
__global__ __launch_bounds__(256) void prep_k(
    const float* __restrict__ x, const float* __restrict__ q_w, const float* __restrict__ kv_w,
    const float* __restrict__ sr_w, const float* __restrict__ proj_w,
    u16* __restrict__ xb, u16* __restrict__ wfused, u16* __restrict__ pwb,
    const float* __restrict__ table, const float* __restrict__ w1, const float* __restrict__ b1,
    const float* __restrict__ w2, const float* __restrict__ b2, float* __restrict__ cpb)
{
    __shared__ float w1s[512][2];
    __shared__ float b1s[512];
    __shared__ float w2s[8][512];
    int bid = blockIdx.x, tid = threadIdx.x;
    if (bid < 4096) {
        int i = bid * 256 + tid;
        float4 v = reinterpret_cast<const float4*>(x)[i];
        ushort4 o; o.x = f2b(v.x); o.y = f2b(v.y); o.z = f2b(v.z); o.w = f2b(v.w);
        reinterpret_cast<ushort4*>(xb)[i] = o;
    } else if (bid < 4416) {
        int i = (bid - 4096) * 256 + tid;
        const float* s; u16* d; int off;
        if (i < 16384)      { s = q_w;    d = wfused; off = i; }
        else if (i < 49152) { s = kv_w;   d = wfused; off = i; }
        else if (i < 65536) { s = sr_w;   d = wfused; off = i; }
        else                { s = proj_w; d = pwb;    off = i - 65536; }
        int soff = (i < 16384) ? i : (i < 49152) ? (i - 16384) : (i < 65536) ? (i - 49152) : (i - 65536);
        float4 v = reinterpret_cast<const float4*>(s)[soff];
        ushort4 o; o.x = f2b(v.x); o.y = f2b(v.y); o.z = f2b(v.z); o.w = f2b(v.w);
        reinterpret_cast<ushort4*>(d)[off] = o;
    } else {
        for (int i = tid; i < 512; i += 256) {
            w1s[i][0] = w1[i * 2]; w1s[i][1] = w1[i * 2 + 1]; b1s[i] = b1[i];
        }
        for (int i = tid; i < 4096; i += 256) w2s[i >> 9][i & 511] = w2[i];
        __syncthreads();
        int t = (bid - 4416) * 256 + tid;
        float t0 = table[t * 2], t1 = table[t * 2 + 1];
        float acc[8] = {};
        for (int j = 0; j < 512; ++j) {
            float h = fmaxf(t0 * w1s[j][0] + t1 * w1s[j][1] + b1s[j], 0.0f);
            #pragma unroll
            for (int hh = 0; hh < 8; ++hh) acc[hh] += h * w2s[hh][j];
        }
        #pragma unroll
        for (int hh = 0; hh < 8; ++hh) cpb[t * 8 + hh] = acc[hh] + b2[hh];
    }
}

// ---------------- LDS-staged MFMA GEMM, 64-col B stripe resident in LDS ----------------
// MODE 0: fused q/kv/sr. Block tile 256 rows x 64 cols, grid (16, 64).
// MODE 1: proj. Block tile 64 rows x 64 cols, grid (4, 256).
template<int MODE>
__global__ __launch_bounds__(256) void gemm_big_k(
    const u16* __restrict__ A, const u16* __restrict__ W,
    const float* __restrict__ b0, const float* __restrict__ b1, const float* __restrict__ b2,
    float* __restrict__ qn, float* __restrict__ kv, u16* __restrict__ xgb, float* __restrict__ pout)
{
    constexpr int RI = (MODE == 0) ? 4 : 1;
    __shared__ u16 Bs[64 * 264];
    int tid = threadIdx.x, w = tid >> 6, lane = tid & 63;
    int quad = lane >> 4, l16 = lane & 15;
    int colBase = blockIdx.x * 64;
    // stage B: 64 cols x 256 k, padded stride 264
    #pragma unroll
    for (int c = 0; c < 8; ++c) {
        int linear = c * 256 + tid;
        int col = linear >> 5, kc = linear & 31;
        uint4 v = *reinterpret_cast<const uint4*>(W + (size_t)(colBase + col) * 256 + kc * 8);
        *reinterpret_cast<uint4*>(&Bs[col * 264 + kc * 8]) = v;
    }
    __syncthreads();
    int rowBase = blockIdx.y * (RI * 64) + w * (RI * 16);
    f32x4 acc[RI][4] = {};
    const u16* aptr = A + (size_t)(rowBase + l16) * 256 + quad * 8;
    #pragma unroll
    for (int k0 = 0; k0 < 256; k0 += 32) {
        bf16x8 af[RI];
        #pragma unroll
        for (int i = 0; i < RI; ++i)
            af[i] = *reinterpret_cast<const bf16x8*>(aptr + (size_t)i * 16 * 256 + k0);
        #pragma unroll
        for (int j = 0; j < 4; ++j) {
            bf16x8 bfr = *reinterpret_cast<const bf16x8*>(&Bs[(j * 16 + l16) * 264 + k0 + quad * 8]);
            #pragma unroll
            for (int i = 0; i < RI; ++i)
                acc[i][j] = __builtin_amdgcn_mfma_f32_16x16x32_bf16(af[i], bfr, acc[i][j], 0, 0, 0);
        }
    }
    int rng = (MODE == 0) ? (colBase >> 8) : 99;   // 0:q 1:kv-k 2:kv-v 3:sr
    float bj[4];
    #pragma unroll
    for (int j = 0; j < 4; ++j) {
        int gc = colBase + j * 16 + l16;
        if (MODE == 1)      bj[j] = b0[gc];
        else if (rng == 0)  bj[j] = b0[gc];
        else if (rng <= 2)  bj[j] = b1[gc - 256];
        else                bj[j] = b2[gc - 768];
    }
    #pragma unroll
    for (int i = 0; i < RI; ++i) {
        float vals[4][4];
        #pragma unroll
        for (int j = 0; j < 4; ++j)
            #pragma unroll
            for (int r = 0; r < 4; ++r) {
                float t = acc[i][j][r] + bj[j];
                if (MODE == 0 && rng == 3) t = 0.5f * t * (1.0f + erff(t * 0.70710678118654752f));
                vals[j][r] = t;
            }
        if (MODE == 0 && rng <= 1) {
            #pragma unroll
            for (int hp = 0; hp < 2; ++hp)
                #pragma unroll
                for (int r = 0; r < 4; ++r) {
                    float s = vals[2*hp][r] * vals[2*hp][r] + vals[2*hp+1][r] * vals[2*hp+1][r];
                    s += __shfl_xor(s, 1); s += __shfl_xor(s, 2);
                    s += __shfl_xor(s, 4); s += __shfl_xor(s, 8);
                    float inv = 1.0f / fmaxf(sqrtf(s), 1e-12f);
                    vals[2*hp][r] *= inv; vals[2*hp+1][r] *= inv;
                }
        }
        #pragma unroll
        for (int j = 0; j < 4; ++j) {
            int gc = colBase + j * 16 + l16;
            #pragma unroll
            for (int r = 0; r < 4; ++r) {
                int row = rowBase + i * 16 + quad * 4 + r;
                if (MODE == 1)      pout[(size_t)row * 256 + gc] = vals[j][r];
                else if (rng == 0)  qn[(size_t)row * 256 + gc] = vals[j][r];
                else if (rng <= 2)  kv[(size_t)row * 512 + gc - 256] = vals[j][r];
                else                xgb[(size_t)row * 256 + gc - 768] = f2b(vals[j][r]);
            }
        }
    }
}

// ---------------- fused avgpool + LN + kv_pool GEMM + k-norm: 2 blocks per (b,p) ----------------
__global__ __launch_bounds__(256) void poolkv_k(
    const u16* __restrict__ xgb, const float* __restrict__ g, const float* __restrict__ bta,
    const float* __restrict__ kv_w, const float* __restrict__ kv_b, float* __restrict__ kvp)
{
    __shared__ __align__(16) float xps[256];
    __shared__ float r1[4], r2[4];
    int bid = blockIdx.x;
    int bp = bid >> 1, half = bid & 1;
    int b = bp >> 6, p = bp & 63;
    int py = p >> 3, px = p & 7;
    int o = threadIdx.x;
    float s = 0.0f;
    for (int sy = 0; sy < 8; ++sy)
        #pragma unroll
        for (int sx = 0; sx < 8; ++sx) {
            int pix = (py * 8 + sy) * 64 + px * 8 + sx;
            s += b2f(xgb[((size_t)(b * N_ + pix)) * C_ + o]);
        }
    float v = s * (1.0f / 64.0f);
    float s1 = v, s2 = v * v;
    #pragma unroll
    for (int off = 32; off >= 1; off >>= 1) { s1 += __shfl_xor(s1, off); s2 += __shfl_xor(s2, off); }
    int wv = o >> 6, ln = o & 63;
    if (ln == 0) { r1[wv] = s1; r2[wv] = s2; }
    __syncthreads();
    float S1 = r1[0] + r1[1] + r1[2] + r1[3];
    float S2 = r2[0] + r2[1] + r2[2] + r2[3];
    float mu = S1 * (1.0f / 256.0f);
    float var = S2 * (1.0f / 256.0f) - mu * mu;
    xps[o] = (v - mu) * rsqrtf(var + 1e-5f) * g[o] + bta[o];
    __syncthreads();
    int col = half * 256 + o;
    float a = kv_b[col];
    const float4* xp4 = (const float4*)xps;
    const float4* wrow = (const float4*)(kv_w + (size_t)col * 256);
    #pragma unroll 8
    for (int k4 = 0; k4 < 64; ++k4) {
        float4 xv = xp4[k4]; float4 wa = wrow[k4];
        a += xv.x * wa.x + xv.y * wa.y + xv.z * wa.z + xv.w * wa.w;
    }
    if (half == 0) {
        float ss = a * a;
        ss += __shfl_xor(ss, 1); ss += __shfl_xor(ss, 2); ss += __shfl_xor(ss, 4);
        ss += __shfl_xor(ss, 8); ss += __shfl_xor(ss, 16);
        a *= 1.0f / fmaxf(sqrtf(ss), 1e-12f);
    }
    kvp[(size_t)bp * 512 + col] = a;
}

// ---------------- MFMA fused attention (re-strided LDS: S_w 76, aw_s separate) ----------------
__global__ __launch_bounds__(256) void attn_k(
    const float* __restrict__ qn, const float* __restrict__ kv,
    const float* __restrict__ kvp, const float* __restrict__ cpb,
    const int* __restrict__ rpi, const float* __restrict__ temp,
    const float* __restrict__ qe, const float* __restrict__ lt,
    const float* __restrict__ rpb, const float* __restrict__ lb,
    const float* __restrict__ slsin, u16* __restrict__ aob)
{
    __shared__ u16 kp_hi[64 * 40], kp_lo[64 * 40];
    __shared__ u16 vp_hi[32 * 72], vp_lo[32 * 72];
    __shared__ u16 ltb[16 * 32];
    __shared__ float qs_w[4][16][36];
    __shared__ float S_w[4][16][76];
    __shared__ float aw_s[4][16][12];
    __shared__ float rpb_s[9], lb_s[9];

    int bid = blockIdx.x;
    int tile = bid & 63, h = (bid >> 6) & 7, b = bid >> 9;
    int tid = threadIdx.x, wave = tid >> 6, lane = tid & 63;
    int quad = lane >> 4, l16 = lane & 15;

    {
        int p = tid >> 2, dc = (tid & 3) * 8;
        const float* src = kvp + ((size_t)(b * P_ + p)) * 512 + h * 32 + dc;
        float4 k0 = *(const float4*)(src), k1 = *(const float4*)(src + 4);
        float4 v0 = *(const float4*)(src + 256), v1 = *(const float4*)(src + 260);
        float kf[8] = {k0.x,k0.y,k0.z,k0.w,k1.x,k1.y,k1.z,k1.w};
        float vf[8] = {v0.x,v0.y,v0.z,v0.w,v1.x,v1.y,v1.z,v1.w};
        #pragma unroll
        for (int j = 0; j < 8; ++j) {
            u16 khi = f2b(kf[j]);
            kp_hi[p * 40 + dc + j] = khi;
            kp_lo[p * 40 + dc + j] = f2b(kf[j] - b2f(khi));
            u16 vhi = f2b(vf[j]);
            vp_hi[(dc + j) * 72 + p] = vhi;
            vp_lo[(dc + j) * 72 + p] = f2b(vf[j] - b2f(vhi));
        }
    }
    for (int t = tid; t < 512; t += 256) {
        int l = t & 15, d = t >> 4;
        ltb[l * 32 + d] = (l < 9) ? f2b(lt[h * 288 + d * 9 + l]) : (u16)0;
    }
    if (tid < 9) { rpb_s[tid] = rpb[h * 9 + tid]; lb_s[tid] = lb[h * 9 + tid]; }
    float tsc = log1pf(expf(temp[h]));
    __syncthreads();

    int n0w = tile * 64 + wave * 16;
    bf16x8 qs_hi, qs_lo, qn_b;
    {
        int n = n0w + l16;
        const float* qptr = qn + ((size_t)(b * N_ + n)) * C_ + h * 32 + quad * 8;
        float4 q0 = *(const float4*)qptr, q1 = *(const float4*)(qptr + 4);
        const float* qeptr = qe + h * 32 + quad * 8;
        float4 e0 = *(const float4*)qeptr, e1 = *(const float4*)(qeptr + 4);
        float slv = slsin[n];
        float qf[8] = {q0.x,q0.y,q0.z,q0.w,q1.x,q1.y,q1.z,q1.w};
        float ef[8] = {e0.x,e0.y,e0.z,e0.w,e1.x,e1.y,e1.z,e1.w};
        #pragma unroll
        for (int j = 0; j < 8; ++j) {
            float qs = (qf[j] + ef[j]) * tsc * slv;
            u16 hi = f2b(qs);
            qs_hi[j] = (short)hi;
            qs_lo[j] = f2bs(qs - b2f(hi));
            qn_b[j]  = f2bs(qf[j]);
            qs_w[wave][l16][quad * 8 + j] = qs;
        }
        if (quad == 0) { S_w[wave][l16][73] = NEG_; S_w[wave][l16][74] = NEG_; S_w[wave][l16][75] = NEG_; }
    }

    #pragma unroll
    for (int jt = 0; jt < 4; ++jt) {
        bf16x8 bh = *(const bf16x8*)&kp_hi[(jt * 16 + l16) * 40 + quad * 8];
        bf16x8 bl = *(const bf16x8*)&kp_lo[(jt * 16 + l16) * 40 + quad * 8];
        f32x4 a = {};
        a = __builtin_amdgcn_mfma_f32_16x16x32_bf16(qs_lo, bh, a, 0, 0, 0);
        a = __builtin_amdgcn_mfma_f32_16x16x32_bf16(qs_hi, bl, a, 0, 0, 0);
        a = __builtin_amdgcn_mfma_f32_16x16x32_bf16(qs_hi, bh, a, 0, 0, 0);
        #pragma unroll
        for (int r = 0; r < 4; ++r) {
            int pix = quad * 4 + r;
            int n = n0w + pix;
            int idx = rpi[n * P_ + jt * 16 + l16];
            S_w[wave][pix][jt * 16 + l16] = a[r] + cpb[(size_t)idx * 8 + h];
        }
    }
    f32x4 accL;
    {
        bf16x8 ltf = *(const bf16x8*)&ltb[l16 * 32 + quad * 8];
        f32x4 z = {};
        accL = __builtin_amdgcn_mfma_f32_16x16x32_bf16(qn_b, ltf, z, 0, 0, 0);
    }
    for (int t = lane; t < 144; t += 64) {
        int pix = t / 9, l = t - pix * 9;
        int n = n0w + pix, y = n >> 6, x = n & 63;
        int ny = y + l / 3 - 1, nx = x + (l % 3) - 1;
        bool ok = ((unsigned)ny < 64u) && ((unsigned)nx < 64u);
        int nn = ok ? ny * 64 + nx : n;
        const float4* kb = (const float4*)(kv + ((size_t)(b * N_ + nn)) * 512 + h * 32);
        float acl = 0.0f;
        #pragma unroll
        for (int d4 = 0; d4 < 8; ++d4) {
            float4 kk = kb[d4];
            float4 qq = *(const float4*)&qs_w[wave][pix][d4 * 4];
            acl += qq.x * kk.x + qq.y * kk.y + qq.z * kk.z + qq.w * kk.w;
        }
        S_w[wave][pix][64 + l] = ok ? (acl + rpb_s[l]) : NEG_;
    }
    {
        int pix = lane >> 2, c0 = (lane & 3) * 19;
        float vals[19]; float mx = NEG_;
        #pragma unroll
        for (int i = 0; i < 19; ++i) { vals[i] = S_w[wave][pix][c0 + i]; mx = fmaxf(mx, vals[i]); }
        mx = fmaxf(mx, __shfl_xor(mx, 1));
        mx = fmaxf(mx, __shfl_xor(mx, 2));
        float sm = 0.0f;
        #pragma unroll
        for (int i = 0; i < 19; ++i) { vals[i] = expf(vals[i] - mx); sm += vals[i]; }
        sm += __shfl_xor(sm, 1); sm += __shfl_xor(sm, 2);
        float inv = 1.0f / sm;
        #pragma unroll
        for (int i = 0; i < 19; ++i) S_w[wave][pix][c0 + i] = vals[i] * inv;
    }
    if (l16 < 9) {
        #pragma unroll
        for (int r = 0; r < 4; ++r) {
            int pix = quad * 4 + r;
            int n = n0w + pix, y = n >> 6, x = n & 63;
            int ny = y + l16 / 3 - 1, nx = x + (l16 % 3) - 1;
            bool ok = ((unsigned)ny < 64u) && ((unsigned)nx < 64u);
            aw_s[wave][pix][l16] = ok ? (accL[r] + lb_s[l16] + S_w[wave][pix][64 + l16]) : 0.0f;
        }
    }
    f32x4 accO[2] = {};
    #pragma unroll
    for (int kc = 0; kc < 2; ++kc) {
        float wf[8];
        *(float4*)&wf[0] = *(const float4*)&S_w[wave][l16][kc * 32 + quad * 8];
        *(float4*)&wf[4] = *(const float4*)&S_w[wave][l16][kc * 32 + quad * 8 + 4];
        bf16x8 w_hi, w_lo;
        #pragma unroll
        for (int j = 0; j < 8; ++j) {
            u16 hi = f2b(wf[j]);
            w_hi[j] = (short)hi;
            w_lo[j] = f2bs(wf[j] - b2f(hi));
        }
        #pragma unroll
        for (int nt = 0; nt < 2; ++nt) {
            bf16x8 vh = *(const bf16x8*)&vp_hi[(nt * 16 + l16) * 72 + kc * 32 + quad * 8];
            bf16x8 vl = *(const bf16x8*)&vp_lo[(nt * 16 + l16) * 72 + kc * 32 + quad * 8];
            accO[nt] = __builtin_amdgcn_mfma_f32_16x16x32_bf16(w_lo, vh, accO[nt], 0, 0, 0);
            accO[nt] = __builtin_amdgcn_mfma_f32_16x16x32_bf16(w_hi, vl, accO[nt], 0, 0, 0);
            accO[nt] = __builtin_amdgcn_mfma_f32_16x16x32_bf16(w_hi, vh, accO[nt], 0, 0, 0);
        }
    }
    #pragma unroll
    for (int r = 0; r < 4; ++r) {
        int pix = quad * 4 + r;
        int n = n0w + pix, y = n >> 6, x = n & 63;
        #pragma unroll
        for (int l = 0; l < 9; ++l) {
            int ny = y + l / 3 - 1, nx = x + (l % 3) - 1;
            bool ok = ((unsigned)ny < 64u) && ((unsigned)nx < 64u);
            int nn = ok ? ny * 64 + nx : n;
            float aw = aw_s[wave][pix][l];
            const float* vb = kv + ((size_t)(b * N_ + nn)) * 512 + 256 + h * 32;
            accO[0][r] += aw * vb[l16];
            accO[1][r] += aw * vb[16 + l16];
        }
    }
    #pragma unroll
    for (int nt = 0; nt < 2; ++nt)
        #pragma unroll
        for (int r = 0; r < 4; ++r) {
            int n = n0w + quad * 4 + r;
            aob[((size_t)(b * N_ + n)) * C_ + h * 32 + nt * 16 + l16] = f2b(accO[nt][r]);
        }
}

extern "C" void kernel_launch(void* const* d_in, const int* in_sizes, int n_in,
                              void* d_out, int out_size, void* d_ws, size_t ws_size,
                              hipStream_t stream) {
    const float* x      = (const float*)d_in[0];
    const int*   rpi    = (const int*)d_in[1];
    const float* table  = (const float*)d_in[2];
    const float* q_w    = (const float*)d_in[3];
    const float* q_b    = (const float*)d_in[4];
    const float* kv_w   = (const float*)d_in[5];
    const float* kv_b   = (const float*)d_in[6];
    const float* temp   = (const float*)d_in[7];
    const float* qe     = (const float*)d_in[8];
    const float* proj_w = (const float*)d_in[9];
    const float* proj_b = (const float*)d_in[10];
    const float* sr_w   = (const float*)d_in[11];
    const float* sr_b   = (const float*)d_in[12];
    const float* norm_g = (const float*)d_in[13];
    const float* norm_b = (const float*)d_in[14];
    const float* cpb1_w = (const float*)d_in[15];
    const float* cpb1_b = (const float*)d_in[16];
    const float* cpb2_w = (const float*)d_in[17];
    const float* cpb2_b = (const float*)d_in[18];
    const float* rpb    = (const float*)d_in[19];
    const float* lt     = (const float*)d_in[20];
    const float* lb     = (const float*)d_in[21];
    const float* sls    = (const float*)d_in[22];

    float* ws  = (float*)d_ws;
    float* qn  = ws;                                   // B*N*C fp32
    float* kv  = qn  + (size_t)B_ * N_ * C_;           // B*N*2C fp32
    float* kvp = kv  + (size_t)B_ * N_ * 2 * C_;       // B*P*2C fp32
    float* cpb = kvp + (size_t)B_ * P_ * 2 * C_;       // T*NH fp32
    u16*   xb  = (u16*)(cpb + (size_t)T_ * NH_);       // B*N*C bf16
    u16*   wfb = xb  + (size_t)B_ * N_ * C_;           // 1024*256 bf16 (q;kv;sr)
    u16*   pwb = wfb + (size_t)1024 * C_;              // C*C bf16
    u16*   xgb = pwb + (size_t)C_ * C_;                // B*N*C bf16 (gelu out; reused as attn out)
    u16*   aob = xgb;

    dim3 blk(256);

    // 1) prep
    prep_k<<<dim3(4432), blk, 0, stream>>>(x, q_w, kv_w, sr_w, proj_w, xb, wfb, pwb,
                                           table, cpb1_w, cpb1_b, cpb2_w, cpb2_b, cpb);
    // 2) fused GEMM (LDS-staged): qn (l2norm), kv (k l2norm), xgb (gelu bf16)
    gemm_big_k<0><<<dim3(16, 64), blk, 0, stream>>>(xb, wfb, q_b, kv_b, sr_b, qn, kv, xgb, nullptr);
    // 3) pool + LN + kv_pool + k-norm (split halves)
    poolkv_k<<<dim3(B_ * P_ * 2), blk, 0, stream>>>(xgb, norm_g, norm_b, kv_w, kv_b, kvp);
    // 4) fused MFMA attention -> aob (bf16)
    attn_k<<<dim3(B_ * NH_ * 64), blk, 0, stream>>>(qn, kv, kvp, cpb, rpi, temp, qe, lt, rpb, lb, sls, aob);
    // 5) proj -> d_out (fp32)
    gemm_big_k<1><<<dim3(4, 256), blk, 0, stream>>>(aob, pwb, proj_b, nullptr, nullptr,
                                                    nullptr, nullptr, nullptr, (float*)d_out);
}

// Round 8
// 274.520 us; speedup vs baseline: 3.7332x; 1.0107x over previous
//
#include <hip/hip_runtime.h>
#include <hip/hip_bf16.h>

typedef unsigned short u16;
typedef unsigned int u32;

#define B_ 4
#define N_ 4096
#define C_ 256
#define NH_ 8
#define HD_ 32
#define L_ 9
#define P_ 64
#define T_ 4096
#define NEG_ (-1e30f)

typedef __attribute__((ext_vector_type(8))) short bf16x8;
typedef __attribute__((ext_vector_type(4))) float f32x4;

__device__ __forceinline__ float b2f(u16 u) {
    union { u32 i; float f; } v; v.i = ((u32)u) << 16; return v.f;
}
__device__ __forceinline__ u16 f2b(float f) {
    u32 x = __float_as_uint(f);
    u32 r = (x + 0x7fffu + ((x >> 16) & 1u)) >> 16;
    return (u16)r;
}
__device__ __forceinline__ short f2bs(float f) { return (short)f2b(f); }

// ---------------- prep: x->bf16, weights->bf16 (fused W), CPB MLP — one launch ----------------
__global__ __launch_bounds__(256) void prep_k(
    const float* __restrict__ x, const float* __restrict__ q_w, const float* __restrict__ kv_w,
    const float* __restrict__ sr_w, const float* __restrict__ proj_w,
    u16* __restrict__ xb, u16* __restrict__ wfused, u16* __restrict__ pwb,
    const float* __restrict__ table, const float* __restrict__ w1, const float* __restrict__ b1,
    const float* __restrict__ w2, const float* __restrict__ b2, float* __restrict__ cpb)
{
    __shared__ float w1s[512][2];
    __shared__ float b1s[512];
    __shared__ float w2s[8][512];
    int bid = blockIdx.x, tid = threadIdx.x;
    if (bid < 4096) {
        int i = bid * 256 + tid;
        float4 v = reinterpret_cast<const float4*>(x)[i];
        ushort4 o; o.x = f2b(v.x); o.y = f2b(v.y); o.z = f2b(v.z); o.w = f2b(v.w);
        reinterpret_cast<ushort4*>(xb)[i] = o;
    } else if (bid < 4416) {
        int i = (bid - 4096) * 256 + tid;
        const float* s; u16* d; int off;
        if (i < 16384)      { s = q_w;    d = wfused; off = i; }
        else if (i < 49152) { s = kv_w;   d = wfused; off = i; }
        else if (i < 65536) { s = sr_w;   d = wfused; off = i; }
        else                { s = proj_w; d = pwb;    off = i - 65536; }
        int soff = (i < 16384) ? i : (i < 49152) ? (i - 16384) : (i < 65536) ? (i - 49152) : (i - 65536);
        float4 v = reinterpret_cast<const float4*>(s)[soff];
        ushort4 o; o.x = f2b(v.x); o.y = f2b(v.y); o.z = f2b(v.z); o.w = f2b(v.w);
        reinterpret_cast<ushort4*>(d)[off] = o;
    } else {
        for (int i = tid; i < 512; i += 256) {
            w1s[i][0] = w1[i * 2]; w1s[i][1] = w1[i * 2 + 1]; b1s[i] = b1[i];
        }
        for (int i = tid; i < 4096; i += 256) w2s[i >> 9][i & 511] = w2[i];
        __syncthreads();
        int t = (bid - 4416) * 256 + tid;
        float t0 = table[t * 2], t1 = table[t * 2 + 1];
        float acc[8] = {};
        for (int j = 0; j < 512; ++j) {
            float h = fmaxf(t0 * w1s[j][0] + t1 * w1s[j][1] + b1s[j], 0.0f);
            #pragma unroll
            for (int hh = 0; hh < 8; ++hh) acc[hh] += h * w2s[hh][j];
        }
        #pragma unroll
        for (int hh = 0; hh < 8; ++hh) cpb[t * 8 + hh] = acc[hh] + b2[hh];
    }
}

// ---------------- LDS-staged MFMA GEMM, 64-col B stripe resident in LDS ----------------
// MODE 0: fused q/kv/sr. Block tile 256 rows x 64 cols, grid (16, 64).
// MODE 1: proj. Block tile 64 rows x 64 cols, grid (4, 256).
template<int MODE>
__global__ __launch_bounds__(256) void gemm_big_k(
    const u16* __restrict__ A, const u16* __restrict__ W,
    const float* __restrict__ b0, const float* __restrict__ b1, const float* __restrict__ b2,
    float* __restrict__ qn, float* __restrict__ kv, u16* __restrict__ xgb, float* __restrict__ pout)
{
    constexpr int RI = (MODE == 0) ? 4 : 1;
    __shared__ u16 Bs[64 * 264];
    int tid = threadIdx.x, w = tid >> 6, lane = tid & 63;
    int quad = lane >> 4, l16 = lane & 15;
    int colBase = blockIdx.x * 64;
    #pragma unroll
    for (int c = 0; c < 8; ++c) {
        int linear = c * 256 + tid;
        int col = linear >> 5, kc = linear & 31;
        uint4 v = *reinterpret_cast<const uint4*>(W + (size_t)(colBase + col) * 256 + kc * 8);
        *reinterpret_cast<uint4*>(&Bs[col * 264 + kc * 8]) = v;
    }
    __syncthreads();
    int rowBase = blockIdx.y * (RI * 64) + w * (RI * 16);
    f32x4 acc[RI][4] = {};
    const u16* aptr = A + (size_t)(rowBase + l16) * 256 + quad * 8;
    // 1-deep A prefetch
    bf16x8 afc[RI];
    #pragma unroll
    for (int i = 0; i < RI; ++i) afc[i] = *reinterpret_cast<const bf16x8*>(aptr + (size_t)i * 16 * 256);
    #pragma unroll
    for (int k0 = 0; k0 < 256; k0 += 32) {
        bf16x8 afn[RI];
        if (k0 < 224) {
            #pragma unroll
            for (int i = 0; i < RI; ++i)
                afn[i] = *reinterpret_cast<const bf16x8*>(aptr + (size_t)i * 16 * 256 + k0 + 32);
        }
        #pragma unroll
        for (int j = 0; j < 4; ++j) {
            bf16x8 bfr = *reinterpret_cast<const bf16x8*>(&Bs[(j * 16 + l16) * 264 + k0 + quad * 8]);
            #pragma unroll
            for (int i = 0; i < RI; ++i)
                acc[i][j] = __builtin_amdgcn_mfma_f32_16x16x32_bf16(afc[i], bfr, acc[i][j], 0, 0, 0);
        }
        if (k0 < 224) {
            #pragma unroll
            for (int i = 0; i < RI; ++i) afc[i] = afn[i];
        }
    }
    int rng = (MODE == 0) ? (colBase >> 8) : 99;   // 0:q 1:kv-k 2:kv-v 3:sr
    float bj[4];
    #pragma unroll
    for (int j = 0; j < 4; ++j) {
        int gc = colBase + j * 16 + l16;
        if (MODE == 1)      bj[j] = b0[gc];
        else if (rng == 0)  bj[j] = b0[gc];
        else if (rng <= 2)  bj[j] = b1[gc - 256];
        else                bj[j] = b2[gc - 768];
    }
    #pragma unroll
    for (int i = 0; i < RI; ++i) {
        float vals[4][4];
        #pragma unroll
        for (int j = 0; j < 4; ++j)
            #pragma unroll
            for (int r = 0; r < 4; ++r) {
                float t = acc[i][j][r] + bj[j];
                if (MODE == 0 && rng == 3) t = 0.5f * t * (1.0f + erff(t * 0.70710678118654752f));
                vals[j][r] = t;
            }
        if (MODE == 0 && rng <= 1) {
            #pragma unroll
            for (int hp = 0; hp < 2; ++hp)
                #pragma unroll
                for (int r = 0; r < 4; ++r) {
                    float s = vals[2*hp][r] * vals[2*hp][r] + vals[2*hp+1][r] * vals[2*hp+1][r];
                    s += __shfl_xor(s, 1); s += __shfl_xor(s, 2);
                    s += __shfl_xor(s, 4); s += __shfl_xor(s, 8);
                    float inv = 1.0f / fmaxf(sqrtf(s), 1e-12f);
                    vals[2*hp][r] *= inv; vals[2*hp+1][r] *= inv;
                }
        }
        #pragma unroll
        for (int j = 0; j < 4; ++j) {
            int gc = colBase + j * 16 + l16;
            #pragma unroll
            for (int r = 0; r < 4; ++r) {
                int row = rowBase + i * 16 + quad * 4 + r;
                if (MODE == 1)      pout[(size_t)row * 256 + gc] = vals[j][r];
                else if (rng == 0)  qn[(size_t)row * 256 + gc] = vals[j][r];
                else if (rng <= 2)  kv[(size_t)row * 512 + gc - 256] = vals[j][r];
                else                xgb[(size_t)row * 256 + gc - 768] = f2b(vals[j][r]);
            }
        }
    }
}

// ---------------- fused avgpool + LN + kv_pool GEMM + k-norm: 2 blocks per (b,p) ----------------
__global__ __launch_bounds__(256) void poolkv_k(
    const u16* __restrict__ xgb, const float* __restrict__ g, const float* __restrict__ bta,
    const float* __restrict__ kv_w, const float* __restrict__ kv_b, float* __restrict__ kvp)
{
    __shared__ __align__(16) float xps[256];
    __shared__ float r1[4], r2[4];
    int bid = blockIdx.x;
    int bp = bid >> 1, half = bid & 1;
    int b = bp >> 6, p = bp & 63;
    int py = p >> 3, px = p & 7;
    int o = threadIdx.x;
    float s = 0.0f;
    for (int sy = 0; sy < 8; ++sy)
        #pragma unroll
        for (int sx = 0; sx < 8; ++sx) {
            int pix = (py * 8 + sy) * 64 + px * 8 + sx;
            s += b2f(xgb[((size_t)(b * N_ + pix)) * C_ + o]);
        }
    float v = s * (1.0f / 64.0f);
    float s1 = v, s2 = v * v;
    #pragma unroll
    for (int off = 32; off >= 1; off >>= 1) { s1 += __shfl_xor(s1, off); s2 += __shfl_xor(s2, off); }
    int wv = o >> 6, ln = o & 63;
    if (ln == 0) { r1[wv] = s1; r2[wv] = s2; }
    __syncthreads();
    float S1 = r1[0] + r1[1] + r1[2] + r1[3];
    float S2 = r2[0] + r2[1] + r2[2] + r2[3];
    float mu = S1 * (1.0f / 256.0f);
    float var = S2 * (1.0f / 256.0f) - mu * mu;
    xps[o] = (v - mu) * rsqrtf(var + 1e-5f) * g[o] + bta[o];
    __syncthreads();
    int col = half * 256 + o;
    float a = kv_b[col];
    const float4* xp4 = (const float4*)xps;
    const float4* wrow = (const float4*)(kv_w + (size_t)col * 256);
    #pragma unroll 8
    for (int k4 = 0; k4 < 64; ++k4) {
        float4 xv = xp4[k4]; float4 wa = wrow[k4];
        a += xv.x * wa.x + xv.y * wa.y + xv.z * wa.z + xv.w * wa.w;
    }
    if (half == 0) {
        float ss = a * a;
        ss += __shfl_xor(ss, 1); ss += __shfl_xor(ss, 2); ss += __shfl_xor(ss, 4);
        ss += __shfl_xor(ss, 8); ss += __shfl_xor(ss, 16);
        a *= 1.0f / fmaxf(sqrtf(ss), 1e-12f);
    }
    kvp[(size_t)bp * 512 + col] = a;
}

// ---------------- MFMA fused attention: LDS diet (39.1 KB -> 4 blocks/CU) ----------------
// local 3x3 logits use register-held q-fragment + cross-quad shfl reduction (no qs_w LDS);
// combined local weights overwrite S_w cols 64..72 (no aw_s).
__global__ __launch_bounds__(256) void attn_k(
    const float* __restrict__ qn, const float* __restrict__ kv,
    const float* __restrict__ kvp, const float* __restrict__ cpb,
    const int* __restrict__ rpi, const float* __restrict__ temp,
    const float* __restrict__ qe, const float* __restrict__ lt,
    const float* __restrict__ rpb, const float* __restrict__ lb,
    const float* __restrict__ slsin, u16* __restrict__ aob)
{
    __shared__ u16 kp_hi[64 * 40], kp_lo[64 * 40];
    __shared__ u16 vp_hi[32 * 72], vp_lo[32 * 72];
    __shared__ u16 ltb[16 * 32];
    __shared__ float S_w[4][16][76];
    __shared__ float rpb_s[9], lb_s[9];

    int bid = blockIdx.x;
    int tile = bid & 63, h = (bid >> 6) & 7, b = bid >> 9;
    int tid = threadIdx.x, wave = tid >> 6, lane = tid & 63;
    int quad = lane >> 4, l16 = lane & 15;

    {
        int p = tid >> 2, dc = (tid & 3) * 8;
        const float* src = kvp + ((size_t)(b * P_ + p)) * 512 + h * 32 + dc;
        float4 k0 = *(const float4*)(src), k1 = *(const float4*)(src + 4);
        float4 v0 = *(const float4*)(src + 256), v1 = *(const float4*)(src + 260);
        float kf[8] = {k0.x,k0.y,k0.z,k0.w,k1.x,k1.y,k1.z,k1.w};
        float vf[8] = {v0.x,v0.y,v0.z,v0.w,v1.x,v1.y,v1.z,v1.w};
        #pragma unroll
        for (int j = 0; j < 8; ++j) {
            u16 khi = f2b(kf[j]);
            kp_hi[p * 40 + dc + j] = khi;
            kp_lo[p * 40 + dc + j] = f2b(kf[j] - b2f(khi));
            u16 vhi = f2b(vf[j]);
            vp_hi[(dc + j) * 72 + p] = vhi;
            vp_lo[(dc + j) * 72 + p] = f2b(vf[j] - b2f(vhi));
        }
    }
    for (int t = tid; t < 512; t += 256) {
        int l = t & 15, d = t >> 4;
        ltb[l * 32 + d] = (l < 9) ? f2b(lt[h * 288 + d * 9 + l]) : (u16)0;
    }
    if (tid < 9) { rpb_s[tid] = rpb[h * 9 + tid]; lb_s[tid] = lb[h * 9 + tid]; }
    float tsc = log1pf(expf(temp[h]));
    __syncthreads();

    int n0w = tile * 64 + wave * 16;
    bf16x8 qs_hi, qs_lo, qn_b;
    float qsr[8];
    {
        int n = n0w + l16;
        const float* qptr = qn + ((size_t)(b * N_ + n)) * C_ + h * 32 + quad * 8;
        float4 q0 = *(const float4*)qptr, q1 = *(const float4*)(qptr + 4);
        const float* qeptr = qe + h * 32 + quad * 8;
        float4 e0 = *(const float4*)qeptr, e1 = *(const float4*)(qeptr + 4);
        float slv = slsin[n];
        float qf[8] = {q0.x,q0.y,q0.z,q0.w,q1.x,q1.y,q1.z,q1.w};
        float ef[8] = {e0.x,e0.y,e0.z,e0.w,e1.x,e1.y,e1.z,e1.w};
        #pragma unroll
        for (int j = 0; j < 8; ++j) {
            float qs = (qf[j] + ef[j]) * tsc * slv;
            u16 hi = f2b(qs);
            qs_hi[j] = (short)hi;
            qs_lo[j] = f2bs(qs - b2f(hi));
            qn_b[j]  = f2bs(qf[j]);
            qsr[j] = qs;
        }
        if (quad == 0) { S_w[wave][l16][73] = NEG_; S_w[wave][l16][74] = NEG_; S_w[wave][l16][75] = NEG_; }
    }

    // ---- pool logits (12 MFMA, compensated) + bias gather ----
    #pragma unroll
    for (int jt = 0; jt < 4; ++jt) {
        bf16x8 bh = *(const bf16x8*)&kp_hi[(jt * 16 + l16) * 40 + quad * 8];
        bf16x8 bl = *(const bf16x8*)&kp_lo[(jt * 16 + l16) * 40 + quad * 8];
        f32x4 a = {};
        a = __builtin_amdgcn_mfma_f32_16x16x32_bf16(qs_lo, bh, a, 0, 0, 0);
        a = __builtin_amdgcn_mfma_f32_16x16x32_bf16(qs_hi, bl, a, 0, 0, 0);
        a = __builtin_amdgcn_mfma_f32_16x16x32_bf16(qs_hi, bh, a, 0, 0, 0);
        #pragma unroll
        for (int r = 0; r < 4; ++r) {
            int pix = quad * 4 + r;
            int n = n0w + pix;
            int idx = rpi[n * P_ + jt * 16 + l16];
            S_w[wave][pix][jt * 16 + l16] = a[r] + cpb[(size_t)idx * 8 + h];
        }
    }
    // ---- learnable-token logits (1 MFMA) ----
    f32x4 accL;
    {
        bf16x8 ltf = *(const bf16x8*)&ltb[l16 * 32 + quad * 8];
        f32x4 z = {};
        accL = __builtin_amdgcn_mfma_f32_16x16x32_bf16(qn_b, ltf, z, 0, 0, 0);
    }
    // ---- local 3x3 logits: register qs + cross-quad shuffle reduce ----
    #pragma unroll
    for (int l = 0; l < 9; ++l) {
        int n = n0w + l16, y = n >> 6, x = n & 63;
        int ny = y + l / 3 - 1, nx = x + (l % 3) - 1;
        bool ok = ((unsigned)ny < 64u) && ((unsigned)nx < 64u);
        int nn = ok ? ny * 64 + nx : n;
        const float4* kb = (const float4*)(kv + ((size_t)(b * N_ + nn)) * 512 + h * 32 + quad * 8);
        float4 k0v = kb[0], k1v = kb[1];
        float part = qsr[0]*k0v.x + qsr[1]*k0v.y + qsr[2]*k0v.z + qsr[3]*k0v.w
                   + qsr[4]*k1v.x + qsr[5]*k1v.y + qsr[6]*k1v.z + qsr[7]*k1v.w;
        part += __shfl_xor(part, 16);
        part += __shfl_xor(part, 32);
        if (quad == 0) S_w[wave][l16][64 + l] = ok ? (part + rpb_s[l]) : NEG_;
    }
    // ---- softmax over 73 (4 lanes per pixel, 19 cols each) ----
    {
        int pix = lane >> 2, c0 = (lane & 3) * 19;
        float vals[19]; float mx = NEG_;
        #pragma unroll
        for (int i = 0; i < 19; ++i) { vals[i] = S_w[wave][pix][c0 + i]; mx = fmaxf(mx, vals[i]); }
        mx = fmaxf(mx, __shfl_xor(mx, 1));
        mx = fmaxf(mx, __shfl_xor(mx, 2));
        float sm = 0.0f;
        #pragma unroll
        for (int i = 0; i < 19; ++i) { vals[i] = expf(vals[i] - mx); sm += vals[i]; }
        sm += __shfl_xor(sm, 1); sm += __shfl_xor(sm, 2);
        float inv = 1.0f / sm;
        #pragma unroll
        for (int i = 0; i < 19; ++i) S_w[wave][pix][c0 + i] = vals[i] * inv;
    }
    // ---- combined local weights overwrite S_w cols 64..72 ----
    if (l16 < 9) {
        #pragma unroll
        for (int r = 0; r < 4; ++r) {
            int pix = quad * 4 + r;
            int n = n0w + pix, y = n >> 6, x = n & 63;
            int ny = y + l16 / 3 - 1, nx = x + (l16 % 3) - 1;
            bool ok = ((unsigned)ny < 64u) && ((unsigned)nx < 64u);
            float prev = S_w[wave][pix][64 + l16];
            S_w[wave][pix][64 + l16] = ok ? (accL[r] + lb_s[l16] + prev) : 0.0f;
        }
    }
    // ---- PV (12 MFMA, compensated) + local-V (fp32 VALU) ----
    f32x4 accO[2] = {};
    #pragma unroll
    for (int kc = 0; kc < 2; ++kc) {
        float wf[8];
        *(float4*)&wf[0] = *(const float4*)&S_w[wave][l16][kc * 32 + quad * 8];
        *(float4*)&wf[4] = *(const float4*)&S_w[wave][l16][kc * 32 + quad * 8 + 4];
        bf16x8 w_hi, w_lo;
        #pragma unroll
        for (int j = 0; j < 8; ++j) {
            u16 hi = f2b(wf[j]);
            w_hi[j] = (short)hi;
            w_lo[j] = f2bs(wf[j] - b2f(hi));
        }
        #pragma unroll
        for (int nt = 0; nt < 2; ++nt) {
            bf16x8 vh = *(const bf16x8*)&vp_hi[(nt * 16 + l16) * 72 + kc * 32 + quad * 8];
            bf16x8 vl = *(const bf16x8*)&vp_lo[(nt * 16 + l16) * 72 + kc * 32 + quad * 8];
            accO[nt] = __builtin_amdgcn_mfma_f32_16x16x32_bf16(w_lo, vh, accO[nt], 0, 0, 0);
            accO[nt] = __builtin_amdgcn_mfma_f32_16x16x32_bf16(w_hi, vl, accO[nt], 0, 0, 0);
            accO[nt] = __builtin_amdgcn_mfma_f32_16x16x32_bf16(w_hi, vh, accO[nt], 0, 0, 0);
        }
    }
    #pragma unroll
    for (int r = 0; r < 4; ++r) {
        int pix = quad * 4 + r;
        int n = n0w + pix, y = n >> 6, x = n & 63;
        #pragma unroll
        for (int l = 0; l < 9; ++l) {
            int ny = y + l / 3 - 1, nx = x + (l % 3) - 1;
            bool ok = ((unsigned)ny < 64u) && ((unsigned)nx < 64u);
            int nn = ok ? ny * 64 + nx : n;
            float aw = S_w[wave][pix][64 + l];
            const float* vb = kv + ((size_t)(b * N_ + nn)) * 512 + 256 + h * 32;
            accO[0][r] += aw * vb[l16];
            accO[1][r] += aw * vb[16 + l16];
        }
    }
    #pragma unroll
    for (int nt = 0; nt < 2; ++nt)
        #pragma unroll
        for (int r = 0; r < 4; ++r) {
            int n = n0w + quad * 4 + r;
            aob[((size_t)(b * N_ + n)) * C_ + h * 32 + nt * 16 + l16] = f2b(accO[nt][r]);
        }
}

extern "C" void kernel_launch(void* const* d_in, const int* in_sizes, int n_in,
                              void* d_out, int out_size, void* d_ws, size_t ws_size,
                              hipStream_t stream) {
    const float* x      = (const float*)d_in[0];
    const int*   rpi    = (const int*)d_in[1];
    const float* table  = (const float*)d_in[2];
    const float* q_w    = (const float*)d_in[3];
    const float* q_b    = (const float*)d_in[4];
    const float* kv_w   = (const float*)d_in[5];
    const float* kv_b   = (const float*)d_in[6];
    const float* temp   = (const float*)d_in[7];
    const float* qe     = (const float*)d_in[8];
    const float* proj_w = (const float*)d_in[9];
    const float* proj_b = (const float*)d_in[10];
    const float* sr_w   = (const float*)d_in[11];
    const float* sr_b   = (const float*)d_in[12];
    const float* norm_g = (const float*)d_in[13];
    const float* norm_b = (const float*)d_in[14];
    const float* cpb1_w = (const float*)d_in[15];
    const float* cpb1_b = (const float*)d_in[16];
    const float* cpb2_w = (const float*)d_in[17];
    const float* cpb2_b = (const float*)d_in[18];
    const float* rpb    = (const float*)d_in[19];
    const float* lt     = (const float*)d_in[20];
    const float* lb     = (const float*)d_in[21];
    const float* sls    = (const float*)d_in[22];

    float* ws  = (float*)d_ws;
    float* qn  = ws;                                   // B*N*C fp32
    float* kv  = qn  + (size_t)B_ * N_ * C_;           // B*N*2C fp32
    float* kvp = kv  + (size_t)B_ * N_ * 2 * C_;       // B*P*2C fp32
    float* cpb = kvp + (size_t)B_ * P_ * 2 * C_;       // T*NH fp32
    u16*   xb  = (u16*)(cpb + (size_t)T_ * NH_);       // B*N*C bf16
    u16*   wfb = xb  + (size_t)B_ * N_ * C_;           // 1024*256 bf16 (q;kv;sr)
    u16*   pwb = wfb + (size_t)1024 * C_;              // C*C bf16
    u16*   xgb = pwb + (size_t)C_ * C_;                // B*N*C bf16 (gelu out; reused as attn out)
    u16*   aob = xgb;

    dim3 blk(256);

    prep_k<<<dim3(4432), blk, 0, stream>>>(x, q_w, kv_w, sr_w, proj_w, xb, wfb, pwb,
                                           table, cpb1_w, cpb1_b, cpb2_w, cpb2_b, cpb);
    gemm_big_k<0><<<dim3(16, 64), blk, 0, stream>>>(xb, wfb, q_b, kv_b, sr_b, qn, kv, xgb, nullptr);
    poolkv_k<<<dim3(B_ * P_ * 2), blk, 0, stream>>>(xgb, norm_g, norm_b, kv_w, kv_b, kvp);
    attn_k<<<dim3(B_ * NH_ * 64), blk, 0, stream>>>(qn, kv, kvp, cpb, rpi, temp, qe, lt, rpb, lb, sls, aob);
    gemm_big_k<1><<<dim3(4, 256), blk, 0, stream>>>(aob, pwb, proj_b, nullptr, nullptr,
                                                    nullptr, nullptr, nullptr, (float*)d_out);
}

// Round 9
// 266.286 us; speedup vs baseline: 3.8486x; 1.0309x over previous
//
#include <hip/hip_runtime.h>
#include <hip/hip_bf16.h>

typedef unsigned short u16;
typedef unsigned int u32;

#define B_ 4
#define N_ 4096
#define C_ 256
#define NH_ 8
#define HD_ 32
#define L_ 9
#define P_ 64
#define T_ 4096
#define NEG_ (-1e30f)

typedef __attribute__((ext_vector_type(8))) short bf16x8;
typedef __attribute__((ext_vector_type(4))) float f32x4;

__device__ __forceinline__ float b2f(u16 u) {
    union { u32 i; float f; } v; v.i = ((u32)u) << 16; return v.f;
}
__device__ __forceinline__ u16 f2b(float f) {
    u32 x = __float_as_uint(f);
    u32 r = (x + 0x7fffu + ((x >> 16) & 1u)) >> 16;
    return (u16)r;
}
__device__ __forceinline__ short f2bs(float f) { return (short)f2b(f); }

// ---------------- prep: x->bf16, weights->bf16 (fused W), CPB MLP — one launch ----------------
__global__ __launch_bounds__(256) void prep_k(
    const float* __restrict__ x, const float* __restrict__ q_w, const float* __restrict__ kv_w,
    const float* __restrict__ sr_w, const float* __restrict__ proj_w,
    u16* __restrict__ xb, u16* __restrict__ wfused, u16* __restrict__ pwb,
    const float* __restrict__ table, const float* __restrict__ w1, const float* __restrict__ b1,
    const float* __restrict__ w2, const float* __restrict__ b2, float* __restrict__ cpb)
{
    __shared__ float w1s[512][2];
    __shared__ float b1s[512];
    __shared__ float w2s[8][512];
    int bid = blockIdx.x, tid = threadIdx.x;
    if (bid < 4096) {
        int i = bid * 256 + tid;
        float4 v = reinterpret_cast<const float4*>(x)[i];
        ushort4 o; o.x = f2b(v.x); o.y = f2b(v.y); o.z = f2b(v.z); o.w = f2b(v.w);
        reinterpret_cast<ushort4*>(xb)[i] = o;
    } else if (bid < 4416) {
        int i = (bid - 4096) * 256 + tid;
        const float* s; u16* d; int off;
        if (i < 16384)      { s = q_w;    d = wfused; off = i; }
        else if (i < 49152) { s = kv_w;   d = wfused; off = i; }
        else if (i < 65536) { s = sr_w;   d = wfused; off = i; }
        else                { s = proj_w; d = pwb;    off = i - 65536; }
        int soff = (i < 16384) ? i : (i < 49152) ? (i - 16384) : (i < 65536) ? (i - 49152) : (i - 65536);
        float4 v = reinterpret_cast<const float4*>(s)[soff];
        ushort4 o; o.x = f2b(v.x); o.y = f2b(v.y); o.z = f2b(v.z); o.w = f2b(v.w);
        reinterpret_cast<ushort4*>(d)[off] = o;
    } else {
        for (int i = tid; i < 512; i += 256) {
            w1s[i][0] = w1[i * 2]; w1s[i][1] = w1[i * 2 + 1]; b1s[i] = b1[i];
        }
        for (int i = tid; i < 4096; i += 256) w2s[i >> 9][i & 511] = w2[i];
        __syncthreads();
        int t = (bid - 4416) * 256 + tid;
        float t0 = table[t * 2], t1 = table[t * 2 + 1];
        float acc[8] = {};
        for (int j = 0; j < 512; ++j) {
            float h = fmaxf(t0 * w1s[j][0] + t1 * w1s[j][1] + b1s[j], 0.0f);
            #pragma unroll
            for (int hh = 0; hh < 8; ++hh) acc[hh] += h * w2s[hh][j];
        }
        #pragma unroll
        for (int hh = 0; hh < 8; ++hh) cpb[t * 8 + hh] = acc[hh] + b2[hh];
    }
}

// ---------------- LDS-staged MFMA GEMM ----------------
// MODE 0: fused kv/sr (cols 256..1023 of wfused). Block tile 256 rows x 64 cols, grid (12, 64).
//         rng 1: kv-k -> kvk fp32 (l2norm); rng 2: kv-v -> kvv bf16; rng 3: sr -> xgb bf16 (gelu)
// MODE 1: proj. Block tile 128 rows x 64 cols, grid (4, 128).
template<int MODE>
__global__ __launch_bounds__(256) void gemm_big_k(
    const u16* __restrict__ A, const u16* __restrict__ W,
    const float* __restrict__ b0, const float* __restrict__ b1, const float* __restrict__ b2,
    float* __restrict__ kvk, u16* __restrict__ kvv, u16* __restrict__ xgb, float* __restrict__ pout)
{
    constexpr int RI = (MODE == 0) ? 4 : 2;
    __shared__ u16 Bs[64 * 264];
    int tid = threadIdx.x, w = tid >> 6, lane = tid & 63;
    int quad = lane >> 4, l16 = lane & 15;
    int colBase = (MODE == 0 ? 256 : 0) + blockIdx.x * 64;
    #pragma unroll
    for (int c = 0; c < 8; ++c) {
        int linear = c * 256 + tid;
        int col = linear >> 5, kc = linear & 31;
        uint4 v = *reinterpret_cast<const uint4*>(W + (size_t)(colBase + col) * 256 + kc * 8);
        *reinterpret_cast<uint4*>(&Bs[col * 264 + kc * 8]) = v;
    }
    __syncthreads();
    int rowBase = blockIdx.y * (RI * 64) + w * (RI * 16);
    f32x4 acc[RI][4] = {};
    const u16* aptr = A + (size_t)(rowBase + l16) * 256 + quad * 8;
    bf16x8 afc[RI];
    #pragma unroll
    for (int i = 0; i < RI; ++i) afc[i] = *reinterpret_cast<const bf16x8*>(aptr + (size_t)i * 16 * 256);
    #pragma unroll
    for (int k0 = 0; k0 < 256; k0 += 32) {
        bf16x8 afn[RI];
        if (k0 < 224) {
            #pragma unroll
            for (int i = 0; i < RI; ++i)
                afn[i] = *reinterpret_cast<const bf16x8*>(aptr + (size_t)i * 16 * 256 + k0 + 32);
        }
        #pragma unroll
        for (int j = 0; j < 4; ++j) {
            bf16x8 bfr = *reinterpret_cast<const bf16x8*>(&Bs[(j * 16 + l16) * 264 + k0 + quad * 8]);
            #pragma unroll
            for (int i = 0; i < RI; ++i)
                acc[i][j] = __builtin_amdgcn_mfma_f32_16x16x32_bf16(afc[i], bfr, acc[i][j], 0, 0, 0);
        }
        if (k0 < 224) {
            #pragma unroll
            for (int i = 0; i < RI; ++i) afc[i] = afn[i];
        }
    }
    int rng = (MODE == 0) ? (colBase >> 8) : 99;   // 1:kv-k 2:kv-v 3:sr
    float bj[4];
    #pragma unroll
    for (int j = 0; j < 4; ++j) {
        int gc = colBase + j * 16 + l16;
        if (MODE == 1)      bj[j] = b0[gc];
        else if (rng <= 2)  bj[j] = b1[gc - 256];
        else                bj[j] = b2[gc - 768];
    }
    #pragma unroll
    for (int i = 0; i < RI; ++i) {
        float vals[4][4];
        #pragma unroll
        for (int j = 0; j < 4; ++j)
            #pragma unroll
            for (int r = 0; r < 4; ++r) {
                float t = acc[i][j][r] + bj[j];
                if (MODE == 0 && rng == 3) t = 0.5f * t * (1.0f + erff(t * 0.70710678118654752f));
                vals[j][r] = t;
            }
        if (MODE == 0 && rng == 1) {
            #pragma unroll
            for (int hp = 0; hp < 2; ++hp)
                #pragma unroll
                for (int r = 0; r < 4; ++r) {
                    float s = vals[2*hp][r] * vals[2*hp][r] + vals[2*hp+1][r] * vals[2*hp+1][r];
                    s += __shfl_xor(s, 1); s += __shfl_xor(s, 2);
                    s += __shfl_xor(s, 4); s += __shfl_xor(s, 8);
                    float inv = 1.0f / fmaxf(sqrtf(s), 1e-12f);
                    vals[2*hp][r] *= inv; vals[2*hp+1][r] *= inv;
                }
        }
        #pragma unroll
        for (int j = 0; j < 4; ++j) {
            int gc = colBase + j * 16 + l16;
            #pragma unroll
            for (int r = 0; r < 4; ++r) {
                int row = rowBase + i * 16 + quad * 4 + r;
                if (MODE == 1)      pout[(size_t)row * 256 + gc] = vals[j][r];
                else if (rng == 1)  kvk[(size_t)row * 256 + gc - 256] = vals[j][r];
                else if (rng == 2)  kvv[(size_t)row * 256 + gc - 512] = f2b(vals[j][r]);
                else                xgb[(size_t)row * 256 + gc - 768] = f2b(vals[j][r]);
            }
        }
    }
}

// ---------------- fused avgpool+LN+kv_pool+k-norm (blocks 0..511) + bias precompute (512..2559) ----
__global__ __launch_bounds__(256) void poolkv_k(
    const u16* __restrict__ xgb, const float* __restrict__ g, const float* __restrict__ bta,
    const float* __restrict__ kv_w, const float* __restrict__ kv_b, float* __restrict__ kvp,
    const int* __restrict__ rpi, const float* __restrict__ cpb, float* __restrict__ biasp)
{
    int bid = blockIdx.x;
    int tid = threadIdx.x;
    if (bid >= 512) {
        // biasp[(h*N + n)*64 + p] = cpb[rpi[n,p]*8 + h]
        int i = (bid - 512) * 256 + tid;     // 4 elems each, 2,097,152 total
        int e0 = i * 4;
        int p = e0 & 63;
        int hn = e0 >> 6;
        int n = hn & 4095, h = hn >> 12;
        int4 idx4 = *reinterpret_cast<const int4*>(rpi + n * 64 + p);
        float4 o;
        o.x = cpb[(size_t)idx4.x * 8 + h];
        o.y = cpb[(size_t)idx4.y * 8 + h];
        o.z = cpb[(size_t)idx4.z * 8 + h];
        o.w = cpb[(size_t)idx4.w * 8 + h];
        *reinterpret_cast<float4*>(biasp + e0) = o;
        return;
    }
    __shared__ __align__(16) float xps[256];
    __shared__ float r1[4], r2[4];
    int bp = bid >> 1, half = bid & 1;
    int b = bp >> 6, p = bp & 63;
    int py = p >> 3, px = p & 7;
    int o = tid;
    float s = 0.0f;
    for (int sy = 0; sy < 8; ++sy)
        #pragma unroll
        for (int sx = 0; sx < 8; ++sx) {
            int pix = (py * 8 + sy) * 64 + px * 8 + sx;
            s += b2f(xgb[((size_t)(b * N_ + pix)) * C_ + o]);
        }
    float v = s * (1.0f / 64.0f);
    float s1 = v, s2 = v * v;
    #pragma unroll
    for (int off = 32; off >= 1; off >>= 1) { s1 += __shfl_xor(s1, off); s2 += __shfl_xor(s2, off); }
    int wv = o >> 6, ln = o & 63;
    if (ln == 0) { r1[wv] = s1; r2[wv] = s2; }
    __syncthreads();
    float S1 = r1[0] + r1[1] + r1[2] + r1[3];
    float S2 = r2[0] + r2[1] + r2[2] + r2[3];
    float mu = S1 * (1.0f / 256.0f);
    float var = S2 * (1.0f / 256.0f) - mu * mu;
    xps[o] = (v - mu) * rsqrtf(var + 1e-5f) * g[o] + bta[o];
    __syncthreads();
    int col = half * 256 + o;
    float a = kv_b[col];
    const float4* xp4 = (const float4*)xps;
    const float4* wrow = (const float4*)(kv_w + (size_t)col * 256);
    #pragma unroll 8
    for (int k4 = 0; k4 < 64; ++k4) {
        float4 xv = xp4[k4]; float4 wa = wrow[k4];
        a += xv.x * wa.x + xv.y * wa.y + xv.z * wa.z + xv.w * wa.w;
    }
    if (half == 0) {
        float ss = a * a;
        ss += __shfl_xor(ss, 1); ss += __shfl_xor(ss, 2); ss += __shfl_xor(ss, 4);
        ss += __shfl_xor(ss, 8); ss += __shfl_xor(ss, 16);
        a *= 1.0f / fmaxf(sqrtf(ss), 1e-12f);
    }
    kvp[(size_t)bp * 512 + col] = a;
}

// ---------------- MFMA fused attention with fused q-GEMM + precomputed pool bias ----------------
__global__ __launch_bounds__(256) void attn_k(
    const u16* __restrict__ xb, const u16* __restrict__ qwb, const float* __restrict__ q_b,
    const float* __restrict__ kvk, const u16* __restrict__ kvv,
    const float* __restrict__ kvp, const float* __restrict__ biasp,
    const float* __restrict__ temp, const float* __restrict__ qe, const float* __restrict__ lt,
    const float* __restrict__ rpb, const float* __restrict__ lb,
    const float* __restrict__ slsin, u16* __restrict__ aob)
{
    __shared__ u16 kp_hi[64 * 40], kp_lo[64 * 40];
    __shared__ u16 vp_hi[32 * 72], vp_lo[32 * 72];
    __shared__ u16 ltb[16 * 32];
    __shared__ float S_w[4][16][76];
    __shared__ float qs_l[4][16][36];
    __shared__ float rpb_s[9], lb_s[9];

    int bid = blockIdx.x;
    int tile = bid & 63, h = (bid >> 6) & 7, b = bid >> 9;
    int tid = threadIdx.x, wave = tid >> 6, lane = tid & 63;
    int quad = lane >> 4, l16 = lane & 15;

    {
        int p = tid >> 2, dc = (tid & 3) * 8;
        const float* src = kvp + ((size_t)(b * P_ + p)) * 512 + h * 32 + dc;
        float4 k0 = *(const float4*)(src), k1 = *(const float4*)(src + 4);
        float4 v0 = *(const float4*)(src + 256), v1 = *(const float4*)(src + 260);
        float kf[8] = {k0.x,k0.y,k0.z,k0.w,k1.x,k1.y,k1.z,k1.w};
        float vf[8] = {v0.x,v0.y,v0.z,v0.w,v1.x,v1.y,v1.z,v1.w};
        #pragma unroll
        for (int j = 0; j < 8; ++j) {
            u16 khi = f2b(kf[j]);
            kp_hi[p * 40 + dc + j] = khi;
            kp_lo[p * 40 + dc + j] = f2b(kf[j] - b2f(khi));
            u16 vhi = f2b(vf[j]);
            vp_hi[(dc + j) * 72 + p] = vhi;
            vp_lo[(dc + j) * 72 + p] = f2b(vf[j] - b2f(vhi));
        }
    }
    for (int t = tid; t < 512; t += 256) {
        int l = t & 15, d = t >> 4;
        ltb[l * 32 + d] = (l < 9) ? f2b(lt[h * 288 + d * 9 + l]) : (u16)0;
    }
    if (tid < 9) { rpb_s[tid] = rpb[h * 9 + tid]; lb_s[tid] = lb[h * 9 + tid]; }
    float tsc = log1pf(expf(temp[h]));
    __syncthreads();

    int n0w = tile * 64 + wave * 16;

    // ---- fused q-GEMM: 64x32 slice via 16 MFMA ----
    f32x4 qacc[2] = {};
    {
        const u16* xrow = xb + ((size_t)(b * N_ + n0w + l16)) * 256 + quad * 8;
        const u16* qwr  = qwb + ((size_t)(h * 32 + l16)) * 256 + quad * 8;
        #pragma unroll
        for (int k0 = 0; k0 < 256; k0 += 32) {
            bf16x8 ax = *(const bf16x8*)(xrow + k0);
            bf16x8 bw0 = *(const bf16x8*)(qwr + k0);
            bf16x8 bw1 = *(const bf16x8*)(qwr + 16 * 256 + k0);
            qacc[0] = __builtin_amdgcn_mfma_f32_16x16x32_bf16(ax, bw0, qacc[0], 0, 0, 0);
            qacc[1] = __builtin_amdgcn_mfma_f32_16x16x32_bf16(ax, bw1, qacc[1], 0, 0, 0);
        }
    }
    {
        float qb0 = q_b[h * 32 + l16], qb1 = q_b[h * 32 + 16 + l16];
        float qe0 = qe[h * 32 + l16],  qe1 = qe[h * 32 + 16 + l16];
        #pragma unroll
        for (int r = 0; r < 4; ++r) {
            int p = quad * 4 + r;
            float v0 = qacc[0][r] + qb0, v1 = qacc[1][r] + qb1;
            float s = v0 * v0 + v1 * v1;
            s += __shfl_xor(s, 1); s += __shfl_xor(s, 2);
            s += __shfl_xor(s, 4); s += __shfl_xor(s, 8);
            float inv = 1.0f / fmaxf(sqrtf(s), 1e-12f);
            v0 *= inv; v1 *= inv;
            float sc = tsc * slsin[n0w + p];
            qs_l[wave][p][l16]      = (v0 + qe0) * sc;
            qs_l[wave][p][16 + l16] = (v1 + qe1) * sc;
        }
        if (quad == 0) { S_w[wave][l16][73] = NEG_; S_w[wave][l16][74] = NEG_; S_w[wave][l16][75] = NEG_; }
    }
    // ---- rebuild per-lane fragments (A-layout) from qs_l ----
    bf16x8 qs_hi, qs_lo, qn_b;
    float qsr[8];
    {
        *(float4*)&qsr[0] = *(const float4*)&qs_l[wave][l16][quad * 8];
        *(float4*)&qsr[4] = *(const float4*)&qs_l[wave][l16][quad * 8 + 4];
        float invs = 1.0f / (tsc * slsin[n0w + l16]);
        const float* qep = qe + h * 32 + quad * 8;
        float4 e0 = *(const float4*)qep, e1 = *(const float4*)(qep + 4);
        float ef[8] = {e0.x,e0.y,e0.z,e0.w,e1.x,e1.y,e1.z,e1.w};
        #pragma unroll
        for (int j = 0; j < 8; ++j) {
            u16 hi = f2b(qsr[j]);
            qs_hi[j] = (short)hi;
            qs_lo[j] = f2bs(qsr[j] - b2f(hi));
            qn_b[j]  = f2bs(qsr[j] * invs - ef[j]);
        }
    }
    // ---- pool logits (12 MFMA, compensated) + precomputed bias ----
    const float* bp = biasp + (size_t)h * N_ * 64;
    #pragma unroll
    for (int jt = 0; jt < 4; ++jt) {
        bf16x8 bh = *(const bf16x8*)&kp_hi[(jt * 16 + l16) * 40 + quad * 8];
        bf16x8 bl = *(const bf16x8*)&kp_lo[(jt * 16 + l16) * 40 + quad * 8];
        f32x4 a = {};
        a = __builtin_amdgcn_mfma_f32_16x16x32_bf16(qs_lo, bh, a, 0, 0, 0);
        a = __builtin_amdgcn_mfma_f32_16x16x32_bf16(qs_hi, bl, a, 0, 0, 0);
        a = __builtin_amdgcn_mfma_f32_16x16x32_bf16(qs_hi, bh, a, 0, 0, 0);
        #pragma unroll
        for (int r = 0; r < 4; ++r) {
            int pix = quad * 4 + r;
            int n = n0w + pix;
            S_w[wave][pix][jt * 16 + l16] = a[r] + bp[(size_t)n * 64 + jt * 16 + l16];
        }
    }
    // ---- learnable-token logits (1 MFMA) ----
    f32x4 accL;
    {
        bf16x8 ltf = *(const bf16x8*)&ltb[l16 * 32 + quad * 8];
        f32x4 z = {};
        accL = __builtin_amdgcn_mfma_f32_16x16x32_bf16(qn_b, ltf, z, 0, 0, 0);
    }
    // ---- local 3x3 logits: register qs + cross-quad shuffle reduce ----
    #pragma unroll
    for (int l = 0; l < 9; ++l) {
        int n = n0w + l16, y = n >> 6, x = n & 63;
        int ny = y + l / 3 - 1, nx = x + (l % 3) - 1;
        bool ok = ((unsigned)ny < 64u) && ((unsigned)nx < 64u);
        int nn = ok ? ny * 64 + nx : n;
        const float4* kb = (const float4*)(kvk + ((size_t)(b * N_ + nn)) * 256 + h * 32 + quad * 8);
        float4 k0v = kb[0], k1v = kb[1];
        float part = qsr[0]*k0v.x + qsr[1]*k0v.y + qsr[2]*k0v.z + qsr[3]*k0v.w
                   + qsr[4]*k1v.x + qsr[5]*k1v.y + qsr[6]*k1v.z + qsr[7]*k1v.w;
        part += __shfl_xor(part, 16);
        part += __shfl_xor(part, 32);
        if (quad == 0) S_w[wave][l16][64 + l] = ok ? (part + rpb_s[l]) : NEG_;
    }
    // ---- softmax over 73 (4 lanes per pixel, 19 cols each) ----
    {
        int pix = lane >> 2, c0 = (lane & 3) * 19;
        float vals[19]; float mx = NEG_;
        #pragma unroll
        for (int i = 0; i < 19; ++i) { vals[i] = S_w[wave][pix][c0 + i]; mx = fmaxf(mx, vals[i]); }
        mx = fmaxf(mx, __shfl_xor(mx, 1));
        mx = fmaxf(mx, __shfl_xor(mx, 2));
        float sm = 0.0f;
        #pragma unroll
        for (int i = 0; i < 19; ++i) { vals[i] = expf(vals[i] - mx); sm += vals[i]; }
        sm += __shfl_xor(sm, 1); sm += __shfl_xor(sm, 2);
        float inv = 1.0f / sm;
        #pragma unroll
        for (int i = 0; i < 19; ++i) S_w[wave][pix][c0 + i] = vals[i] * inv;
    }
    // ---- combined local weights overwrite S_w cols 64..72 ----
    if (l16 < 9) {
        #pragma unroll
        for (int r = 0; r < 4; ++r) {
            int pix = quad * 4 + r;
            int n = n0w + pix, y = n >> 6, x = n & 63;
            int ny = y + l16 / 3 - 1, nx = x + (l16 % 3) - 1;
            bool ok = ((unsigned)ny < 64u) && ((unsigned)nx < 64u);
            float prev = S_w[wave][pix][64 + l16];
            S_w[wave][pix][64 + l16] = ok ? (accL[r] + lb_s[l16] + prev) : 0.0f;
        }
    }
    // ---- PV (12 MFMA, compensated) + local-V (bf16 loads, fp32 VALU) ----
    f32x4 accO[2] = {};
    #pragma unroll
    for (int kc = 0; kc < 2; ++kc) {
        float wf[8];
        *(float4*)&wf[0] = *(const float4*)&S_w[wave][l16][kc * 32 + quad * 8];
        *(float4*)&wf[4] = *(const float4*)&S_w[wave][l16][kc * 32 + quad * 8 + 4];
        bf16x8 w_hi, w_lo;
        #pragma unroll
        for (int j = 0; j < 8; ++j) {
            u16 hi = f2b(wf[j]);
            w_hi[j] = (short)hi;
            w_lo[j] = f2bs(wf[j] - b2f(hi));
        }
        #pragma unroll
        for (int nt = 0; nt < 2; ++nt) {
            bf16x8 vh = *(const bf16x8*)&vp_hi[(nt * 16 + l16) * 72 + kc * 32 + quad * 8];
            bf16x8 vl = *(const bf16x8*)&vp_lo[(nt * 16 + l16) * 72 + kc * 32 + quad * 8];
            accO[nt] = __builtin_amdgcn_mfma_f32_16x16x32_bf16(w_lo, vh, accO[nt], 0, 0, 0);
            accO[nt] = __builtin_amdgcn_mfma_f32_16x16x32_bf16(w_hi, vl, accO[nt], 0, 0, 0);
            accO[nt] = __builtin_amdgcn_mfma_f32_16x16x32_bf16(w_hi, vh, accO[nt], 0, 0, 0);
        }
    }
    #pragma unroll
    for (int r = 0; r < 4; ++r) {
        int pix = quad * 4 + r;
        int n = n0w + pix, y = n >> 6, x = n & 63;
        #pragma unroll
        for (int l = 0; l < 9; ++l) {
            int ny = y + l / 3 - 1, nx = x + (l % 3) - 1;
            bool ok = ((unsigned)ny < 64u) && ((unsigned)nx < 64u);
            int nn = ok ? ny * 64 + nx : n;
            float aw = S_w[wave][pix][64 + l];
            const u16* vb = kvv + ((size_t)(b * N_ + nn)) * 256 + h * 32;
            accO[0][r] += aw * b2f(vb[l16]);
            accO[1][r] += aw * b2f(vb[16 + l16]);
        }
    }
    #pragma unroll
    for (int nt = 0; nt < 2; ++nt)
        #pragma unroll
        for (int r = 0; r < 4; ++r) {
            int n = n0w + quad * 4 + r;
            aob[((size_t)(b * N_ + n)) * C_ + h * 32 + nt * 16 + l16] = f2b(accO[nt][r]);
        }
}

extern "C" void kernel_launch(void* const* d_in, const int* in_sizes, int n_in,
                              void* d_out, int out_size, void* d_ws, size_t ws_size,
                              hipStream_t stream) {
    const float* x      = (const float*)d_in[0];
    const int*   rpi    = (const int*)d_in[1];
    const float* table  = (const float*)d_in[2];
    const float* q_w    = (const float*)d_in[3];
    const float* q_b    = (const float*)d_in[4];
    const float* kv_w   = (const float*)d_in[5];
    const float* kv_b   = (const float*)d_in[6];
    const float* temp   = (const float*)d_in[7];
    const float* qe     = (const float*)d_in[8];
    const float* proj_w = (const float*)d_in[9];
    const float* proj_b = (const float*)d_in[10];
    const float* sr_w   = (const float*)d_in[11];
    const float* sr_b   = (const float*)d_in[12];
    const float* norm_g = (const float*)d_in[13];
    const float* norm_b = (const float*)d_in[14];
    const float* cpb1_w = (const float*)d_in[15];
    const float* cpb1_b = (const float*)d_in[16];
    const float* cpb2_w = (const float*)d_in[17];
    const float* cpb2_b = (const float*)d_in[18];
    const float* rpb    = (const float*)d_in[19];
    const float* lt     = (const float*)d_in[20];
    const float* lb     = (const float*)d_in[21];
    const float* sls    = (const float*)d_in[22];

    float* ws   = (float*)d_ws;
    float* kvk  = ws;                                   // B*N*C fp32 (k, l2normed)
    float* kvp  = kvk + (size_t)B_ * N_ * C_;           // B*P*2C fp32
    float* cpb  = kvp + (size_t)B_ * P_ * 2 * C_;       // T*NH fp32
    float* bia  = cpb + (size_t)T_ * NH_;               // NH*N*P fp32
    u16*   xb   = (u16*)(bia + (size_t)NH_ * N_ * P_);  // B*N*C bf16
    u16*   wfb  = xb  + (size_t)B_ * N_ * C_;           // 1024*256 bf16 (q;kv;sr)
    u16*   pwb  = wfb + (size_t)1024 * C_;              // C*C bf16
    u16*   kvv  = pwb + (size_t)C_ * C_;                // B*N*C bf16 (v)
    u16*   xgb  = kvv + (size_t)B_ * N_ * C_;           // B*N*C bf16 (gelu out; reused as attn out)
    u16*   aob  = xgb;

    dim3 blk(256);

    prep_k<<<dim3(4432), blk, 0, stream>>>(x, q_w, kv_w, sr_w, proj_w, xb, wfb, pwb,
                                           table, cpb1_w, cpb1_b, cpb2_w, cpb2_b, cpb);
    gemm_big_k<0><<<dim3(12, 64), blk, 0, stream>>>(xb, wfb, nullptr, kv_b, sr_b, kvk, kvv, xgb, nullptr);
    poolkv_k<<<dim3(2560), blk, 0, stream>>>(xgb, norm_g, norm_b, kv_w, kv_b, kvp, rpi, cpb, bia);
    attn_k<<<dim3(B_ * NH_ * 64), blk, 0, stream>>>(xb, wfb, q_b, kvk, kvv, kvp, bia,
                                                    temp, qe, lt, rpb, lb, sls, aob);
    gemm_big_k<1><<<dim3(4, 128), blk, 0, stream>>>(aob, pwb, proj_b, nullptr, nullptr,
                                                    nullptr, nullptr, nullptr, (float*)d_out);
}

// Round 10
// 256.815 us; speedup vs baseline: 3.9905x; 1.0369x over previous
//
#include <hip/hip_runtime.h>
#include <hip/hip_bf16.h>

typedef unsigned short u16;
typedef unsigned int u32;

#define B_ 4
#define N_ 4096
#define C_ 256
#define NH_ 8
#define HD_ 32
#define L_ 9
#define P_ 64
#define T_ 4096
#define NEG_ (-1e30f)

typedef __attribute__((ext_vector_type(8))) short bf16x8;
typedef __attribute__((ext_vector_type(4))) float f32x4;

__device__ __forceinline__ float b2f(u16 u) {
    union { u32 i; float f; } v; v.i = ((u32)u) << 16; return v.f;
}
__device__ __forceinline__ u16 f2b(float f) {
    u32 x = __float_as_uint(f);
    u32 r = (x + 0x7fffu + ((x >> 16) & 1u)) >> 16;
    return (u16)r;
}
__device__ __forceinline__ short f2bs(float f) { return (short)f2b(f); }

// ---------------- prep: x->bf16, weights->bf16 (fused W), CPB MLP — one launch ----------------
__global__ __launch_bounds__(256) void prep_k(
    const float* __restrict__ x, const float* __restrict__ q_w, const float* __restrict__ kv_w,
    const float* __restrict__ sr_w, const float* __restrict__ proj_w,
    u16* __restrict__ xb, u16* __restrict__ wfused, u16* __restrict__ pwb,
    const float* __restrict__ table, const float* __restrict__ w1, const float* __restrict__ b1,
    const float* __restrict__ w2, const float* __restrict__ b2, float* __restrict__ cpb)
{
    __shared__ float w1s[512][2];
    __shared__ float b1s[512];
    __shared__ float w2s[8][512];
    int bid = blockIdx.x, tid = threadIdx.x;
    if (bid < 4096) {
        int i = bid * 256 + tid;
        float4 v = reinterpret_cast<const float4*>(x)[i];
        ushort4 o; o.x = f2b(v.x); o.y = f2b(v.y); o.z = f2b(v.z); o.w = f2b(v.w);
        reinterpret_cast<ushort4*>(xb)[i] = o;
    } else if (bid < 4416) {
        int i = (bid - 4096) * 256 + tid;
        const float* s; u16* d; int off;
        if (i < 16384)      { s = q_w;    d = wfused; off = i; }
        else if (i < 49152) { s = kv_w;   d = wfused; off = i; }
        else if (i < 65536) { s = sr_w;   d = wfused; off = i; }
        else                { s = proj_w; d = pwb;    off = i - 65536; }
        int soff = (i < 16384) ? i : (i < 49152) ? (i - 16384) : (i < 65536) ? (i - 49152) : (i - 65536);
        float4 v = reinterpret_cast<const float4*>(s)[soff];
        ushort4 o; o.x = f2b(v.x); o.y = f2b(v.y); o.z = f2b(v.z); o.w = f2b(v.w);
        reinterpret_cast<ushort4*>(d)[off] = o;
    } else {
        for (int i = tid; i < 512; i += 256) {
            w1s[i][0] = w1[i * 2]; w1s[i][1] = w1[i * 2 + 1]; b1s[i] = b1[i];
        }
        for (int i = tid; i < 4096; i += 256) w2s[i >> 9][i & 511] = w2[i];
        __syncthreads();
        int t = (bid - 4416) * 256 + tid;
        float t0 = table[t * 2], t1 = table[t * 2 + 1];
        float acc[8] = {};
        for (int j = 0; j < 512; ++j) {
            float h = fmaxf(t0 * w1s[j][0] + t1 * w1s[j][1] + b1s[j], 0.0f);
            #pragma unroll
            for (int hh = 0; hh < 8; ++hh) acc[hh] += h * w2s[hh][j];
        }
        #pragma unroll
        for (int hh = 0; hh < 8; ++hh) cpb[t * 8 + hh] = acc[hh] + b2[hh];
    }
}

// ---------------- LDS-staged MFMA GEMM ----------------
// MODE 0: fused kv/sr (cols 256..1023 of wfused). Block tile 256 rows x 64 cols, grid (12, 64).
// MODE 1: proj. Block tile 64 rows x 64 cols, grid (4, 256).
template<int MODE>
__global__ __launch_bounds__(256) void gemm_big_k(
    const u16* __restrict__ A, const u16* __restrict__ W,
    const float* __restrict__ b0, const float* __restrict__ b1, const float* __restrict__ b2,
    float* __restrict__ kvk, u16* __restrict__ kvv, u16* __restrict__ xgb, float* __restrict__ pout)
{
    constexpr int RI = (MODE == 0) ? 4 : 1;
    __shared__ u16 Bs[64 * 264];
    int tid = threadIdx.x, w = tid >> 6, lane = tid & 63;
    int quad = lane >> 4, l16 = lane & 15;
    int colBase = (MODE == 0 ? 256 : 0) + blockIdx.x * 64;
    #pragma unroll
    for (int c = 0; c < 8; ++c) {
        int linear = c * 256 + tid;
        int col = linear >> 5, kc = linear & 31;
        uint4 v = *reinterpret_cast<const uint4*>(W + (size_t)(colBase + col) * 256 + kc * 8);
        *reinterpret_cast<uint4*>(&Bs[col * 264 + kc * 8]) = v;
    }
    __syncthreads();
    int rowBase = blockIdx.y * (RI * 64) + w * (RI * 16);
    f32x4 acc[RI][4] = {};
    const u16* aptr = A + (size_t)(rowBase + l16) * 256 + quad * 8;
    bf16x8 afc[RI];
    #pragma unroll
    for (int i = 0; i < RI; ++i) afc[i] = *reinterpret_cast<const bf16x8*>(aptr + (size_t)i * 16 * 256);
    #pragma unroll
    for (int k0 = 0; k0 < 256; k0 += 32) {
        bf16x8 afn[RI];
        if (k0 < 224) {
            #pragma unroll
            for (int i = 0; i < RI; ++i)
                afn[i] = *reinterpret_cast<const bf16x8*>(aptr + (size_t)i * 16 * 256 + k0 + 32);
        }
        #pragma unroll
        for (int j = 0; j < 4; ++j) {
            bf16x8 bfr = *reinterpret_cast<const bf16x8*>(&Bs[(j * 16 + l16) * 264 + k0 + quad * 8]);
            #pragma unroll
            for (int i = 0; i < RI; ++i)
                acc[i][j] = __builtin_amdgcn_mfma_f32_16x16x32_bf16(afc[i], bfr, acc[i][j], 0, 0, 0);
        }
        if (k0 < 224) {
            #pragma unroll
            for (int i = 0; i < RI; ++i) afc[i] = afn[i];
        }
    }
    int rng = (MODE == 0) ? (colBase >> 8) : 99;   // 1:kv-k 2:kv-v 3:sr
    float bj[4];
    #pragma unroll
    for (int j = 0; j < 4; ++j) {
        int gc = colBase + j * 16 + l16;
        if (MODE == 1)      bj[j] = b0[gc];
        else if (rng <= 2)  bj[j] = b1[gc - 256];
        else                bj[j] = b2[gc - 768];
    }
    #pragma unroll
    for (int i = 0; i < RI; ++i) {
        float vals[4][4];
        #pragma unroll
        for (int j = 0; j < 4; ++j)
            #pragma unroll
            for (int r = 0; r < 4; ++r) {
                float t = acc[i][j][r] + bj[j];
                if (MODE == 0 && rng == 3) t = 0.5f * t * (1.0f + erff(t * 0.70710678118654752f));
                vals[j][r] = t;
            }
        if (MODE == 0 && rng == 1) {
            #pragma unroll
            for (int hp = 0; hp < 2; ++hp)
                #pragma unroll
                for (int r = 0; r < 4; ++r) {
                    float s = vals[2*hp][r] * vals[2*hp][r] + vals[2*hp+1][r] * vals[2*hp+1][r];
                    s += __shfl_xor(s, 1); s += __shfl_xor(s, 2);
                    s += __shfl_xor(s, 4); s += __shfl_xor(s, 8);
                    float inv = 1.0f / fmaxf(sqrtf(s), 1e-12f);
                    vals[2*hp][r] *= inv; vals[2*hp+1][r] *= inv;
                }
        }
        #pragma unroll
        for (int j = 0; j < 4; ++j) {
            int gc = colBase + j * 16 + l16;
            #pragma unroll
            for (int r = 0; r < 4; ++r) {
                int row = rowBase + i * 16 + quad * 4 + r;
                if (MODE == 1)      pout[(size_t)row * 256 + gc] = vals[j][r];
                else if (rng == 1)  kvk[(size_t)row * 256 + gc - 256] = vals[j][r];
                else if (rng == 2)  kvv[(size_t)row * 256 + gc - 512] = f2b(vals[j][r]);
                else                xgb[(size_t)row * 256 + gc - 768] = f2b(vals[j][r]);
            }
        }
    }
}

// ---------------- fused avgpool+LN+kv_pool+k-norm (blocks 0..511) + bias precompute (512..2559) ----
__global__ __launch_bounds__(256) void poolkv_k(
    const u16* __restrict__ xgb, const float* __restrict__ g, const float* __restrict__ bta,
    const float* __restrict__ kv_w, const float* __restrict__ kv_b, float* __restrict__ kvp,
    const int* __restrict__ rpi, const float* __restrict__ cpb, float* __restrict__ biasp)
{
    int bid = blockIdx.x;
    int tid = threadIdx.x;
    if (bid >= 512) {
        int i = (bid - 512) * 256 + tid;
        int e0 = i * 4;
        int p = e0 & 63;
        int hn = e0 >> 6;
        int n = hn & 4095, h = hn >> 12;
        int4 idx4 = *reinterpret_cast<const int4*>(rpi + n * 64 + p);
        float4 o;
        o.x = cpb[(size_t)idx4.x * 8 + h];
        o.y = cpb[(size_t)idx4.y * 8 + h];
        o.z = cpb[(size_t)idx4.z * 8 + h];
        o.w = cpb[(size_t)idx4.w * 8 + h];
        *reinterpret_cast<float4*>(biasp + e0) = o;
        return;
    }
    __shared__ __align__(16) float xps[256];
    __shared__ float r1[4], r2[4];
    int bp = bid >> 1, half = bid & 1;
    int b = bp >> 6, p = bp & 63;
    int py = p >> 3, px = p & 7;
    int o = tid;
    float s = 0.0f;
    for (int sy = 0; sy < 8; ++sy)
        #pragma unroll
        for (int sx = 0; sx < 8; ++sx) {
            int pix = (py * 8 + sy) * 64 + px * 8 + sx;
            s += b2f(xgb[((size_t)(b * N_ + pix)) * C_ + o]);
        }
    float v = s * (1.0f / 64.0f);
    float s1 = v, s2 = v * v;
    #pragma unroll
    for (int off = 32; off >= 1; off >>= 1) { s1 += __shfl_xor(s1, off); s2 += __shfl_xor(s2, off); }
    int wv = o >> 6, ln = o & 63;
    if (ln == 0) { r1[wv] = s1; r2[wv] = s2; }
    __syncthreads();
    float S1 = r1[0] + r1[1] + r1[2] + r1[3];
    float S2 = r2[0] + r2[1] + r2[2] + r2[3];
    float mu = S1 * (1.0f / 256.0f);
    float var = S2 * (1.0f / 256.0f) - mu * mu;
    xps[o] = (v - mu) * rsqrtf(var + 1e-5f) * g[o] + bta[o];
    __syncthreads();
    int col = half * 256 + o;
    float a = kv_b[col];
    const float4* xp4 = (const float4*)xps;
    const float4* wrow = (const float4*)(kv_w + (size_t)col * 256);
    #pragma unroll 8
    for (int k4 = 0; k4 < 64; ++k4) {
        float4 xv = xp4[k4]; float4 wa = wrow[k4];
        a += xv.x * wa.x + xv.y * wa.y + xv.z * wa.z + xv.w * wa.w;
    }
    if (half == 0) {
        float ss = a * a;
        ss += __shfl_xor(ss, 1); ss += __shfl_xor(ss, 2); ss += __shfl_xor(ss, 4);
        ss += __shfl_xor(ss, 8); ss += __shfl_xor(ss, 16);
        a *= 1.0f / fmaxf(sqrtf(ss), 1e-12f);
    }
    kvp[(size_t)bp * 512 + col] = a;
}

// ---------------- MFMA fused attention: 2-tile loop, no vp_lo, column-shared local-V ----------------
__global__ __launch_bounds__(256) void attn_k(
    const u16* __restrict__ xb, const u16* __restrict__ qwb, const float* __restrict__ q_b,
    const float* __restrict__ kvk, const u16* __restrict__ kvv,
    const float* __restrict__ kvp, const float* __restrict__ biasp,
    const float* __restrict__ temp, const float* __restrict__ qe, const float* __restrict__ lt,
    const float* __restrict__ rpb, const float* __restrict__ lb,
    const float* __restrict__ slsin, u16* __restrict__ aob)
{
    __shared__ u16 kp_hi[64 * 40], kp_lo[64 * 40];
    __shared__ u16 vp_hi[32 * 72];
    __shared__ u16 ltb[16 * 32];
    __shared__ float S_w[4][16][76];
    __shared__ float qs_l[4][16][36];
    __shared__ float rpb_s[9], lb_s[9];

    int bid = blockIdx.x;
    int tq = bid & 31, h = (bid >> 5) & 7, b = bid >> 8;
    int tid = threadIdx.x, wave = tid >> 6, lane = tid & 63;
    int quad = lane >> 4, l16 = lane & 15;

    {
        int p = tid >> 2, dc = (tid & 3) * 8;
        const float* src = kvp + ((size_t)(b * P_ + p)) * 512 + h * 32 + dc;
        float4 k0 = *(const float4*)(src), k1 = *(const float4*)(src + 4);
        float4 v0 = *(const float4*)(src + 256), v1 = *(const float4*)(src + 260);
        float kf[8] = {k0.x,k0.y,k0.z,k0.w,k1.x,k1.y,k1.z,k1.w};
        float vf[8] = {v0.x,v0.y,v0.z,v0.w,v1.x,v1.y,v1.z,v1.w};
        #pragma unroll
        for (int j = 0; j < 8; ++j) {
            u16 khi = f2b(kf[j]);
            kp_hi[p * 40 + dc + j] = khi;
            kp_lo[p * 40 + dc + j] = f2b(kf[j] - b2f(khi));
            vp_hi[(dc + j) * 72 + p] = f2b(vf[j]);
        }
    }
    for (int t = tid; t < 512; t += 256) {
        int l = t & 15, d = t >> 4;
        ltb[l * 32 + d] = (l < 9) ? f2b(lt[h * 288 + d * 9 + l]) : (u16)0;
    }
    if (tid < 9) { rpb_s[tid] = rpb[h * 9 + tid]; lb_s[tid] = lb[h * 9 + tid]; }
    float tsc = log1pf(expf(temp[h]));
    __syncthreads();

    const float* bp_h = biasp + (size_t)h * N_ * 64;

    for (int it = 0; it < 2; ++it) {
        int tile = tq * 2 + it;
        int n0w = tile * 64 + wave * 16;
        int y = tile;

        // ---- fused q-GEMM: 64x32 slice via 16 MFMA ----
        f32x4 qacc[2] = {};
        {
            const u16* xrow = xb + ((size_t)(b * N_ + n0w + l16)) * 256 + quad * 8;
            const u16* qwr  = qwb + ((size_t)(h * 32 + l16)) * 256 + quad * 8;
            #pragma unroll
            for (int k0 = 0; k0 < 256; k0 += 32) {
                bf16x8 ax = *(const bf16x8*)(xrow + k0);
                bf16x8 bw0 = *(const bf16x8*)(qwr + k0);
                bf16x8 bw1 = *(const bf16x8*)(qwr + 16 * 256 + k0);
                qacc[0] = __builtin_amdgcn_mfma_f32_16x16x32_bf16(ax, bw0, qacc[0], 0, 0, 0);
                qacc[1] = __builtin_amdgcn_mfma_f32_16x16x32_bf16(ax, bw1, qacc[1], 0, 0, 0);
            }
        }
        {
            float qb0 = q_b[h * 32 + l16], qb1 = q_b[h * 32 + 16 + l16];
            float qe0 = qe[h * 32 + l16],  qe1 = qe[h * 32 + 16 + l16];
            #pragma unroll
            for (int r = 0; r < 4; ++r) {
                int p = quad * 4 + r;
                float v0 = qacc[0][r] + qb0, v1 = qacc[1][r] + qb1;
                float s = v0 * v0 + v1 * v1;
                s += __shfl_xor(s, 1); s += __shfl_xor(s, 2);
                s += __shfl_xor(s, 4); s += __shfl_xor(s, 8);
                float inv = 1.0f / fmaxf(sqrtf(s), 1e-12f);
                v0 *= inv; v1 *= inv;
                float sc = tsc * slsin[n0w + p];
                qs_l[wave][p][l16]      = (v0 + qe0) * sc;
                qs_l[wave][p][16 + l16] = (v1 + qe1) * sc;
            }
        }
        // ---- rebuild per-lane fragments (A-layout) from qs_l ----
        bf16x8 qs_hi, qs_lo, qn_b;
        float qsr[8];
        {
            *(float4*)&qsr[0] = *(const float4*)&qs_l[wave][l16][quad * 8];
            *(float4*)&qsr[4] = *(const float4*)&qs_l[wave][l16][quad * 8 + 4];
            float invs = 1.0f / (tsc * slsin[n0w + l16]);
            const float* qep = qe + h * 32 + quad * 8;
            float4 e0 = *(const float4*)qep, e1 = *(const float4*)(qep + 4);
            float ef[8] = {e0.x,e0.y,e0.z,e0.w,e1.x,e1.y,e1.z,e1.w};
            #pragma unroll
            for (int j = 0; j < 8; ++j) {
                u16 hi = f2b(qsr[j]);
                qs_hi[j] = (short)hi;
                qs_lo[j] = f2bs(qsr[j] - b2f(hi));
                qn_b[j]  = f2bs(qsr[j] * invs - ef[j]);
            }
        }
        // ---- pool logits (12 MFMA, compensated) + precomputed bias ----
        #pragma unroll
        for (int jt = 0; jt < 4; ++jt) {
            bf16x8 bh = *(const bf16x8*)&kp_hi[(jt * 16 + l16) * 40 + quad * 8];
            bf16x8 bl = *(const bf16x8*)&kp_lo[(jt * 16 + l16) * 40 + quad * 8];
            f32x4 a = {};
            a = __builtin_amdgcn_mfma_f32_16x16x32_bf16(qs_lo, bh, a, 0, 0, 0);
            a = __builtin_amdgcn_mfma_f32_16x16x32_bf16(qs_hi, bl, a, 0, 0, 0);
            a = __builtin_amdgcn_mfma_f32_16x16x32_bf16(qs_hi, bh, a, 0, 0, 0);
            #pragma unroll
            for (int r = 0; r < 4; ++r) {
                int pix = quad * 4 + r;
                int n = n0w + pix;
                S_w[wave][pix][jt * 16 + l16] = a[r] + bp_h[(size_t)n * 64 + jt * 16 + l16];
            }
        }
        // ---- learnable-token logits (1 MFMA) ----
        f32x4 accL;
        {
            bf16x8 ltf = *(const bf16x8*)&ltb[l16 * 32 + quad * 8];
            f32x4 z = {};
            accL = __builtin_amdgcn_mfma_f32_16x16x32_bf16(qn_b, ltf, z, 0, 0, 0);
        }
        // ---- local 3x3 logits: register qs + cross-quad shuffle reduce ----
        #pragma unroll
        for (int l = 0; l < 9; ++l) {
            int n = n0w + l16, x = n & 63;
            int ny = y + l / 3 - 1, nx = x + (l % 3) - 1;
            bool ok = ((unsigned)ny < 64u) && ((unsigned)nx < 64u);
            int nn = ok ? ny * 64 + nx : n;
            const float4* kb = (const float4*)(kvk + ((size_t)(b * N_ + nn)) * 256 + h * 32 + quad * 8);
            float4 k0v = kb[0], k1v = kb[1];
            float part = qsr[0]*k0v.x + qsr[1]*k0v.y + qsr[2]*k0v.z + qsr[3]*k0v.w
                       + qsr[4]*k1v.x + qsr[5]*k1v.y + qsr[6]*k1v.z + qsr[7]*k1v.w;
            part += __shfl_xor(part, 16);
            part += __shfl_xor(part, 32);
            if (quad == 0) S_w[wave][l16][64 + l] = ok ? (part + rpb_s[l]) : NEG_;
        }
        // ---- re-init NEG pad (softmax of previous tile overwrote it) ----
        if (quad == 0) { S_w[wave][l16][73] = NEG_; S_w[wave][l16][74] = NEG_; S_w[wave][l16][75] = NEG_; }
        // ---- softmax over 73 (4 lanes per pixel, 19 cols each) ----
        {
            int pix = lane >> 2, c0 = (lane & 3) * 19;
            float vals[19]; float mx = NEG_;
            #pragma unroll
            for (int i = 0; i < 19; ++i) { vals[i] = S_w[wave][pix][c0 + i]; mx = fmaxf(mx, vals[i]); }
            mx = fmaxf(mx, __shfl_xor(mx, 1));
            mx = fmaxf(mx, __shfl_xor(mx, 2));
            float sm = 0.0f;
            #pragma unroll
            for (int i = 0; i < 19; ++i) { vals[i] = expf(vals[i] - mx); sm += vals[i]; }
            sm += __shfl_xor(sm, 1); sm += __shfl_xor(sm, 2);
            float inv = 1.0f / sm;
            #pragma unroll
            for (int i = 0; i < 19; ++i) S_w[wave][pix][c0 + i] = vals[i] * inv;
        }
        // ---- combined local weights overwrite S_w cols 64..72 ----
        if (l16 < 9) {
            #pragma unroll
            for (int r = 0; r < 4; ++r) {
                int pix = quad * 4 + r;
                int n = n0w + pix, x = n & 63;
                int ny = y + l16 / 3 - 1, nx = x + (l16 % 3) - 1;
                bool ok = ((unsigned)ny < 64u) && ((unsigned)nx < 64u);
                float prev = S_w[wave][pix][64 + l16];
                S_w[wave][pix][64 + l16] = ok ? (accL[r] + lb_s[l16] + prev) : 0.0f;
            }
        }
        // ---- PV (8 MFMA: (w_hi + w_lo) x v_hi) ----
        f32x4 accO[2] = {};
        #pragma unroll
        for (int kc = 0; kc < 2; ++kc) {
            float wf[8];
            *(float4*)&wf[0] = *(const float4*)&S_w[wave][l16][kc * 32 + quad * 8];
            *(float4*)&wf[4] = *(const float4*)&S_w[wave][l16][kc * 32 + quad * 8 + 4];
            bf16x8 w_hi, w_lo;
            #pragma unroll
            for (int j = 0; j < 8; ++j) {
                u16 hi = f2b(wf[j]);
                w_hi[j] = (short)hi;
                w_lo[j] = f2bs(wf[j] - b2f(hi));
            }
            #pragma unroll
            for (int nt = 0; nt < 2; ++nt) {
                bf16x8 vh = *(const bf16x8*)&vp_hi[(nt * 16 + l16) * 72 + kc * 32 + quad * 8];
                accO[nt] = __builtin_amdgcn_mfma_f32_16x16x32_bf16(w_lo, vh, accO[nt], 0, 0, 0);
                accO[nt] = __builtin_amdgcn_mfma_f32_16x16x32_bf16(w_hi, vh, accO[nt], 0, 0, 0);
            }
        }
        // ---- local-V: shared neighbor columns per quad (18 cols x 2 dims) ----
        {
            int xq0 = wave * 16 + quad * 4;     // x of pixel r=0
            #pragma unroll
            for (int dy = -1; dy <= 1; ++dy) {
                int ny = y + dy;
                bool rowOK = ((unsigned)ny < 64u);
                #pragma unroll
                for (int c = 0; c < 6; ++c) {
                    int xc = xq0 - 1 + c;
                    bool ok = rowOK && ((unsigned)xc < 64u);
                    int nn = ok ? ny * 64 + xc : 0;
                    const u16* vb = kvv + ((size_t)(b * N_ + nn)) * 256 + h * 32;
                    float v0 = b2f(vb[l16]);
                    float v1 = b2f(vb[16 + l16]);
                    #pragma unroll
                    for (int r = 0; r < 4; ++r) {
                        int dxr = c - 1 - r;
                        if (dxr >= -1 && dxr <= 1) {
                            int l = (dy + 1) * 3 + dxr + 1;
                            float aw = S_w[wave][quad * 4 + r][64 + l];
                            accO[0][r] += aw * v0;
                            accO[1][r] += aw * v1;
                        }
                    }
                }
            }
        }
        #pragma unroll
        for (int nt = 0; nt < 2; ++nt)
            #pragma unroll
            for (int r = 0; r < 4; ++r) {
                int n = n0w + quad * 4 + r;
                aob[((size_t)(b * N_ + n)) * C_ + h * 32 + nt * 16 + l16] = f2b(accO[nt][r]);
            }
    }
}

extern "C" void kernel_launch(void* const* d_in, const int* in_sizes, int n_in,
                              void* d_out, int out_size, void* d_ws, size_t ws_size,
                              hipStream_t stream) {
    const float* x      = (const float*)d_in[0];
    const int*   rpi    = (const int*)d_in[1];
    const float* table  = (const float*)d_in[2];
    const float* q_w    = (const float*)d_in[3];
    const float* q_b    = (const float*)d_in[4];
    const float* kv_w   = (const float*)d_in[5];
    const float* kv_b   = (const float*)d_in[6];
    const float* temp   = (const float*)d_in[7];
    const float* qe     = (const float*)d_in[8];
    const float* proj_w = (const float*)d_in[9];
    const float* proj_b = (const float*)d_in[10];
    const float* sr_w   = (const float*)d_in[11];
    const float* sr_b   = (const float*)d_in[12];
    const float* norm_g = (const float*)d_in[13];
    const float* norm_b = (const float*)d_in[14];
    const float* cpb1_w = (const float*)d_in[15];
    const float* cpb1_b = (const float*)d_in[16];
    const float* cpb2_w = (const float*)d_in[17];
    const float* cpb2_b = (const float*)d_in[18];
    const float* rpb    = (const float*)d_in[19];
    const float* lt     = (const float*)d_in[20];
    const float* lb     = (const float*)d_in[21];
    const float* sls    = (const float*)d_in[22];

    float* ws   = (float*)d_ws;
    float* kvk  = ws;                                   // B*N*C fp32 (k, l2normed)
    float* kvp  = kvk + (size_t)B_ * N_ * C_;           // B*P*2C fp32
    float* cpb  = kvp + (size_t)B_ * P_ * 2 * C_;       // T*NH fp32
    float* bia  = cpb + (size_t)T_ * NH_;               // NH*N*P fp32
    u16*   xb   = (u16*)(bia + (size_t)NH_ * N_ * P_);  // B*N*C bf16
    u16*   wfb  = xb  + (size_t)B_ * N_ * C_;           // 1024*256 bf16 (q;kv;sr)
    u16*   pwb  = wfb + (size_t)1024 * C_;              // C*C bf16
    u16*   kvv  = pwb + (size_t)C_ * C_;                // B*N*C bf16 (v)
    u16*   xgb  = kvv + (size_t)B_ * N_ * C_;           // B*N*C bf16 (gelu out; reused as attn out)
    u16*   aob  = xgb;

    dim3 blk(256);

    prep_k<<<dim3(4432), blk, 0, stream>>>(x, q_w, kv_w, sr_w, proj_w, xb, wfb, pwb,
                                           table, cpb1_w, cpb1_b, cpb2_w, cpb2_b, cpb);
    gemm_big_k<0><<<dim3(12, 64), blk, 0, stream>>>(xb, wfb, nullptr, kv_b, sr_b, kvk, kvv, xgb, nullptr);
    poolkv_k<<<dim3(2560), blk, 0, stream>>>(xgb, norm_g, norm_b, kv_w, kv_b, kvp, rpi, cpb, bia);
    attn_k<<<dim3(B_ * NH_ * 32), blk, 0, stream>>>(xb, wfb, q_b, kvk, kvv, kvp, bia,
                                                    temp, qe, lt, rpb, lb, sls, aob);
    gemm_big_k<1><<<dim3(4, 256), blk, 0, stream>>>(aob, pwb, proj_b, nullptr, nullptr,
                                                    nullptr, nullptr, nullptr, (float*)d_out);
}